// Round 1
// baseline (378.365 us; speedup 1.0000x reference)
//
#include <hip/hip_runtime.h>

// SelfAttention: B=4, S=2048, D=1024, H=16, Hd=64. f32 in/out, bf16 MFMA inside.

#define LOG2E 1.4426950408889634f
#define QSCALE (0.125f * LOG2E)   // 1/sqrt(64) * log2(e), folded into Wq/bq

typedef __bf16 bf16x8 __attribute__((ext_vector_type(8)));
typedef float f32x4 __attribute__((ext_vector_type(4)));
typedef unsigned short u16x4 __attribute__((ext_vector_type(4)));
typedef unsigned short u16x8 __attribute__((ext_vector_type(8)));
typedef unsigned int u32x4 __attribute__((ext_vector_type(4)));

__device__ __forceinline__ unsigned short f2bf(float f) {
  unsigned int u = __builtin_bit_cast(unsigned int, f);
  u += 0x7fffu + ((u >> 16) & 1u);   // RNE
  return (unsigned short)(u >> 16);
}

// pack bf16(a) low16, bf16(b) high16; RNE. v_bfe+v_add3 x2 + v_perm.
__device__ __forceinline__ unsigned int pack2bf(float a, float b) {
  unsigned int ua = __builtin_bit_cast(unsigned int, a);
  unsigned int ub = __builtin_bit_cast(unsigned int, b);
  ua += 0x7fffu + ((ua >> 16) & 1u);
  ub += 0x7fffu + ((ub >> 16) & 1u);
  return __builtin_amdgcn_perm(ub, ua, 0x07060302u);
}

typedef const __attribute__((address_space(1))) void* gptr_t;
typedef __attribute__((address_space(3))) void* lptr_t;
__device__ __forceinline__ void gload16(const void* g, void* l) {
  __builtin_amdgcn_global_load_lds((gptr_t)g, (lptr_t)l, 16, 0, 0);
}

// ---------------- merged convert kernel ----------------
__global__ __launch_bounds__(256) void k_cvt(const float* __restrict__ x,
                                             const float* __restrict__ Wq, const float* __restrict__ Wk,
                                             const float* __restrict__ Wv, const float* __restrict__ Wo,
                                             unsigned short* __restrict__ xb, unsigned short* __restrict__ Wb) {
  int gi = (blockIdx.x * 256 + threadIdx.x) * 4;
  if (gi < 8388608) {
    f32x4 v = *(const f32x4*)(x + gi);
    u16x4 o; o[0] = f2bf(v[0]); o[1] = f2bf(v[1]); o[2] = f2bf(v[2]); o[3] = f2bf(v[3]);
    *(u16x4*)(xb + gi) = o;
  } else {
    int i = gi - 8388608;
    int wsel = i >> 20;
    int loc = i & 1048575;
    const float* src = (wsel == 0) ? Wq : (wsel == 1) ? Wk : (wsel == 2) ? Wv : Wo;
    float sc = (wsel == 0) ? QSCALE : 1.0f;
    f32x4 v = *(const f32x4*)(src + loc);
    u16x4 o; o[0] = f2bf(v[0] * sc); o[1] = f2bf(v[1] * sc); o[2] = f2bf(v[2] * sc); o[3] = f2bf(v[3] * sc);
    *(u16x4*)(Wb + i) = o;
  }
}

// ---------------- QKV projection GEMM ----------------
// z=0: Q (pre-scaled) -> [b,h,s,d]; z=1: K -> [b,h,s,d];
// z=2: V -> [b,h,d,s_perm] (pos=8q+4h+r for s=16h+4q+r) so flash PV consumes
//      S^T C-layout regs directly as A-operand fragments.
__global__ __launch_bounds__(256, 2) void k_gemm_qkv(
    const unsigned short* __restrict__ xb, const unsigned short* __restrict__ Wb,
    const float* __restrict__ bq, const float* __restrict__ bk, const float* __restrict__ bv,
    unsigned short* __restrict__ Qb, unsigned short* __restrict__ Kb, unsigned short* __restrict__ Vtb) {
  __shared__ unsigned short As[128 * 32];
  __shared__ unsigned short Bs[128 * 32];
  const int tid = threadIdx.x;
  const int lane = tid & 63;
  const int w = tid >> 6;
  const int wm = w & 1;
  const int wn = w >> 1;
  const int z = blockIdx.z;
  const int m0 = blockIdx.y * 128;
  const int n0 = blockIdx.x * 128;
  const unsigned short* W = Wb + ((size_t)z << 20);

  const int srow = tid >> 2;
  const int sch = (tid & 3) << 3;
  const size_t a0 = (size_t)(m0 + srow) * 1024 + sch;
  const size_t b0 = (size_t)(n0 + srow) * 1024 + sch;

  f32x4 zero4 = {0.f, 0.f, 0.f, 0.f};
  f32x4 acc[4][4];
#pragma unroll
  for (int i = 0; i < 4; ++i)
#pragma unroll
    for (int jj = 0; jj < 4; ++jj) acc[i][jj] = zero4;

  const int fr = lane & 15;
  const int fk = (lane >> 4) << 3;

  for (int kt = 0; kt < 32; ++kt) {
    const int ko = kt << 5;
    __syncthreads();
    gload16(xb + a0 + ko, As + tid * 8);
    gload16(xb + a0 + (size_t)65536 + ko, As + 2048 + tid * 8);
    gload16(W + b0 + ko, Bs + tid * 8);
    gload16(W + b0 + (size_t)65536 + ko, Bs + 2048 + tid * 8);
    __syncthreads();
    bf16x8 af[4], bfr[4];
#pragma unroll
    for (int mt = 0; mt < 4; ++mt)
      af[mt] = *(const bf16x8*)&As[(wm * 64 + mt * 16 + fr) * 32 + fk];
#pragma unroll
    for (int nt = 0; nt < 4; ++nt)
      bfr[nt] = *(const bf16x8*)&Bs[(wn * 64 + nt * 16 + fr) * 32 + fk];
#pragma unroll
    for (int mt = 0; mt < 4; ++mt)
#pragma unroll
      for (int nt = 0; nt < 4; ++nt)
        acc[mt][nt] = __builtin_amdgcn_mfma_f32_16x16x32_bf16(af[mt], bfr[nt], acc[mt][nt], 0, 0, 0);
  }

  const float* bias = (z == 0) ? bq : (z == 1) ? bk : bv;
  const float bsc = (z == 0) ? QSCALE : 1.0f;
  const int rg = (lane >> 4) << 2;
#pragma unroll
  for (int mt = 0; mt < 4; ++mt) {
    const int mb = m0 + wm * 64 + mt * 16 + rg;
    const int b = mb >> 11;
    const int s = mb & 2047;
#pragma unroll
    for (int nt = 0; nt < 4; ++nt) {
      const int n = n0 + wn * 64 + nt * 16 + fr;
      const float bvv = bias[n] * bsc;
      const int h = n >> 6;
      const int d = n & 63;
      if (z == 2) {
        u16x4 pk;
#pragma unroll
        for (int r = 0; r < 4; ++r) pk[r] = f2bf(acc[mt][nt][r] + bvv);
        const int pbase = (s & ~31) | ((s & 12) << 1) | ((s & 16) >> 2);
        *(u16x4*)&Vtb[(((size_t)(b * 16 + h) << 6) + d) * 2048 + pbase] = pk;
      } else {
        unsigned short* O = (z == 0) ? Qb : Kb;
#pragma unroll
        for (int r = 0; r < 4; ++r)
          O[(((size_t)(b * 16 + h) << 11) + s + r) * 64 + d] = f2bf(acc[mt][nt][r] + bvv);
      }
    }
  }
}

// ---------------- flash attention (S^T, no-max softmax, register P, 32q/wave) ----
// r8: software-pipelined staging (T3/T4). Ks double-buffered (32KB), Vts single
// (16KB) -> 48KB LDS keeps 3 blocks/CU. Per j: issue V_j + prefetch K_{j+1},
// compute QK^T from resident K_j, softmax, vmcnt(4)+barrier (V_j visible,
// K_{j+1} still in flight), PV, vmcnt(0)+barrier. Stage latency now hides
// under compute instead of a full drain before every compute phase.
__global__ __launch_bounds__(256, 3) void k_flash(
    const unsigned short* __restrict__ Qb, const unsigned short* __restrict__ Kb,
    const unsigned short* __restrict__ Vtb, unsigned short* __restrict__ Ctx) {
  __shared__ unsigned short Ks[2 * 128 * 64];  // 32KB double-buffered [key][64d], 3-bit chunk xor
  __shared__ unsigned short Vts[64 * 128];     // 16KB [d][128k_perm], 4-bit chunk xor
  const int tid = threadIdx.x;
  const int lane = tid & 63;
  const int wq = tid >> 6;
  const int fr = lane & 15;
  const int qd = lane >> 4;
  const int bh = blockIdx.y;
  const int q0 = blockIdx.x << 7;
  const size_t hoff = (size_t)bh << 17;  // 2048*64
  const unsigned short* Qh = Qb + hoff + ((size_t)q0 << 6);

  // ---- hoisted staging addresses (advance by constant stride per j) ----
  const unsigned short* kg[4];
  const unsigned short* vg[4];
  unsigned short* kl[4];
  unsigned short* vl[4];
#pragma unroll
  for (int p = 0; p < 4; ++p) {
    int slot = p * 256 + tid;
    int kr = slot >> 3, ch = slot & 7;
    kg[p] = Kb + hoff + (size_t)kr * 64 + ((ch ^ (kr & 7)) << 3);
    kl[p] = Ks + slot * 8;
    int dr = slot >> 4, ch2 = slot & 15;
    vg[p] = Vtb + hoff + (size_t)dr * 2048 + ((ch2 ^ (dr & 15)) << 3);
    vl[p] = Vts + slot * 8;
  }

  // ---- hoisted LDS read element-offsets ----
  int kofs[8][2];
#pragma unroll
  for (int kt = 0; kt < 8; ++kt)
#pragma unroll
    for (int ds = 0; ds < 2; ++ds) {
      int key = kt * 16 + fr, c = ds * 4 + qd;
      kofs[kt][ds] = key * 64 + ((c ^ (key & 7)) << 3);
    }
  int vofs[4][4];
#pragma unroll
  for (int ks = 0; ks < 4; ++ks)
#pragma unroll
    for (int dt = 0; dt < 4; ++dt) {
      int d = dt * 16 + fr, c = ks * 4 + qd;
      vofs[ks][dt] = d * 128 + ((c ^ (d & 15)) << 3);
    }

  // Q fragments: B[n=query][k=d]; row = wq*32+qt*16+fr, d = ds*32+qd*8..+7
  bf16x8 qf[2][2];
#pragma unroll
  for (int qt = 0; qt < 2; ++qt)
#pragma unroll
    for (int ds = 0; ds < 2; ++ds)
      qf[qt][ds] = *(const bf16x8*)&Qh[(wq * 32 + qt * 16 + fr) * 64 + ds * 32 + qd * 8];

  f32x4 zero4 = {0.f, 0.f, 0.f, 0.f};
  f32x4 o_acc[2][4];
  float l_p[2] = {0.f, 0.f};
#pragma unroll
  for (int mt = 0; mt < 2; ++mt)
#pragma unroll
    for (int dt = 0; dt < 4; ++dt) o_acc[mt][dt] = zero4;

  // ---- prologue: stage K_0 into buf0, full drain ----
#pragma unroll
  for (int p = 0; p < 4; ++p) gload16(kg[p], kl[p]);
#pragma unroll
  for (int p = 0; p < 4; ++p) kg[p] += 128 * 64;  // -> K_1
  __syncthreads();  // vmcnt(0) + barrier: K_0 visible

  int curoff = 0;  // element offset of current K buffer (0 or 8192)
  for (int j = 0; j < 16; ++j) {
    // invariant at top: K_j visible at Ks+curoff; Vts free (prev PV reads done)
    // issue V_j first (waited by vmcnt(4)), then K_{j+1} prefetch (waited by
    // vmcnt(0) after PV). Last iter's K_17 prefetch reads the next head's K
    // (or start of Vtb for bh=63) -- valid workspace, never consumed.
#pragma unroll
    for (int p = 0; p < 4; ++p) gload16(vg[p], vl[p]);
#pragma unroll
    for (int p = 0; p < 4; ++p) gload16(kg[p], kl[p] + (curoff ^ 8192));
#pragma unroll
    for (int p = 0; p < 4; ++p) { kg[p] += 128 * 64; vg[p] += 128; }

    // ---- S^T = K · Q^T : D[row=key][col=query] (K_j already resident) ----
    f32x4 st[2][8];
#pragma unroll
    for (int qt = 0; qt < 2; ++qt)
#pragma unroll
      for (int kt = 0; kt < 8; ++kt) st[qt][kt] = zero4;
#pragma unroll
    for (int kt = 0; kt < 8; ++kt) {
#pragma unroll
      for (int ds = 0; ds < 2; ++ds) {
        bf16x8 kf = *(const bf16x8*)&Ks[curoff + kofs[kt][ds]];
        st[0][kt] = __builtin_amdgcn_mfma_f32_16x16x32_bf16(kf, qf[0][ds], st[0][kt], 0, 0, 0);
        st[1][kt] = __builtin_amdgcn_mfma_f32_16x16x32_bf16(kf, qf[1][ds], st[1][kt], 0, 0, 0);
      }
    }

    // ---- p = exp2(s) raw; accumulate l in-lane ----
#pragma unroll
    for (int qt = 0; qt < 2; ++qt) {
      float ps0 = 0.f, ps1 = 0.f;
#pragma unroll
      for (int kt = 0; kt < 8; ++kt) {
#pragma unroll
        for (int r = 0; r < 4; ++r) st[qt][kt][r] = __builtin_amdgcn_exp2f(st[qt][kt][r]);
        ps0 += st[qt][kt][0] + st[qt][kt][2];
        ps1 += st[qt][kt][1] + st[qt][kt][3];
      }
      l_p[qt] += ps0 + ps1;
    }

    // V_j done (first 4 issued); K_{j+1} may still be in flight
    asm volatile("s_waitcnt vmcnt(4)" ::: "memory");
    __builtin_amdgcn_s_barrier();

    // ---- O += P · V : A-fragments straight from st regs (permuted-key order) ----
#pragma unroll
    for (int ks = 0; ks < 4; ++ks) {
      bf16x8 pf[2];
#pragma unroll
      for (int mt = 0; mt < 2; ++mt) {
        u32x4 pk;
        pk[0] = pack2bf(st[mt][2 * ks][0], st[mt][2 * ks][1]);
        pk[1] = pack2bf(st[mt][2 * ks][2], st[mt][2 * ks][3]);
        pk[2] = pack2bf(st[mt][2 * ks + 1][0], st[mt][2 * ks + 1][1]);
        pk[3] = pack2bf(st[mt][2 * ks + 1][2], st[mt][2 * ks + 1][3]);
        pf[mt] = __builtin_bit_cast(bf16x8, pk);
      }
#pragma unroll
      for (int dt = 0; dt < 4; ++dt) {
        bf16x8 vf = *(const bf16x8*)&Vts[vofs[ks][dt]];
#pragma unroll
        for (int mt = 0; mt < 2; ++mt)
          o_acc[mt][dt] = __builtin_amdgcn_mfma_f32_16x16x32_bf16(pf[mt], vf, o_acc[mt][dt], 0, 0, 0);
      }
    }

    // K_{j+1} landed; all waves' Vts reads done -> safe to restage next iter
    asm volatile("s_waitcnt vmcnt(0)" ::: "memory");
    __builtin_amdgcn_s_barrier();
    curoff ^= 8192;
  }

  // reduce l across the 4 lanes sharing each query (fr), once
  float l_red[2];
#pragma unroll
  for (int mt = 0; mt < 2; ++mt) {
    float lv = l_p[mt];
    lv += __shfl_xor(lv, 16);
    lv += __shfl_xor(lv, 32);
    l_red[mt] = lv;
  }

  // epilogue: normalize, write context [b][s][h*64+d] bf16
  const int b = bh >> 4;
  const int h = bh & 15;
#pragma unroll
  for (int mt = 0; mt < 2; ++mt) {
#pragma unroll
    for (int r = 0; r < 4; ++r) {
      float lv = __shfl(l_red[mt], qd * 4 + r);
      float rl = 1.0f / lv;
      int s = q0 + wq * 32 + mt * 16 + qd * 4 + r;
      size_t base = (((size_t)b * 2048 + s) << 10) + (h << 6);
#pragma unroll
      for (int dt = 0; dt < 4; ++dt) Ctx[base + dt * 16 + fr] = f2bf(o_acc[mt][dt][r] * rl);
    }
  }
}

// ---------------- output projection GEMM (f32 out) ----------------
__global__ __launch_bounds__(256, 2) void k_gemm_out(
    const unsigned short* __restrict__ Ctx, const unsigned short* __restrict__ Wo,
    const float* __restrict__ bo, float* __restrict__ out) {
  __shared__ unsigned short As[128 * 32];
  __shared__ unsigned short Bs[128 * 32];
  const int tid = threadIdx.x;
  const int lane = tid & 63;
  const int w = tid >> 6;
  const int wm = w & 1;
  const int wn = w >> 1;
  const int m0 = blockIdx.y * 128;
  const int n0 = blockIdx.x * 128;

  const int srow = tid >> 2;
  const int sch = (tid & 3) << 3;
  const size_t a0 = (size_t)(m0 + srow) * 1024 + sch;
  const size_t b0 = (size_t)(n0 + srow) * 1024 + sch;

  f32x4 zero4 = {0.f, 0.f, 0.f, 0.f};
  f32x4 acc[4][4];
#pragma unroll
  for (int i = 0; i < 4; ++i)
#pragma unroll
    for (int jj = 0; jj < 4; ++jj) acc[i][jj] = zero4;

  const int fr = lane & 15;
  const int fk = (lane >> 4) << 3;

  for (int kt = 0; kt < 32; ++kt) {
    const int ko = kt << 5;
    __syncthreads();
    gload16(Ctx + a0 + ko, As + tid * 8);
    gload16(Ctx + a0 + (size_t)65536 + ko, As + 2048 + tid * 8);
    gload16(Wo + b0 + ko, Bs + tid * 8);
    gload16(Wo + b0 + (size_t)65536 + ko, Bs + 2048 + tid * 8);
    __syncthreads();
    bf16x8 af[4], bfr[4];
#pragma unroll
    for (int mt = 0; mt < 4; ++mt)
      af[mt] = *(const bf16x8*)&As[(wm * 64 + mt * 16 + fr) * 32 + fk];
#pragma unroll
    for (int nt = 0; nt < 4; ++nt)
      bfr[nt] = *(const bf16x8*)&Bs[(wn * 64 + nt * 16 + fr) * 32 + fk];
#pragma unroll
    for (int mt = 0; mt < 4; ++mt)
#pragma unroll
      for (int nt = 0; nt < 4; ++nt)
        acc[mt][nt] = __builtin_amdgcn_mfma_f32_16x16x32_bf16(af[mt], bfr[nt], acc[mt][nt], 0, 0, 0);
  }

  const int rg = (lane >> 4) << 2;
#pragma unroll
  for (int mt = 0; mt < 4; ++mt) {
    const int mb = m0 + wm * 64 + mt * 16 + rg;
#pragma unroll
    for (int nt = 0; nt < 4; ++nt) {
      const int n = n0 + wn * 64 + nt * 16 + fr;
      const float bvv = bo[n];
#pragma unroll
      for (int r = 0; r < 4; ++r)
        out[(size_t)(mb + r) * 1024 + n] = acc[mt][nt][r] + bvv;
    }
  }
}

// ---------------- host ----------------
extern "C" void kernel_launch(void* const* d_in, const int* in_sizes, int n_in,
                              void* d_out, int out_size, void* d_ws, size_t ws_size,
                              hipStream_t stream) {
  (void)in_sizes; (void)n_in; (void)out_size; (void)ws_size;
  const float* x = (const float*)d_in[0];
  const float* Wq = (const float*)d_in[1];
  const float* bq = (const float*)d_in[2];
  const float* Wk = (const float*)d_in[3];
  const float* bk = (const float*)d_in[4];
  const float* Wv = (const float*)d_in[5];
  const float* bv = (const float*)d_in[6];
  const float* Wo = (const float*)d_in[7];
  const float* bo = (const float*)d_in[8];
  float* out = (float*)d_out;

  unsigned short* xb = (unsigned short*)d_ws;  // 8388608 el
  unsigned short* Wb = xb + 8388608;           // 4194304 el (q,k,v,o)
  unsigned short* Qb = Wb + 4194304;           // [b,h,s,d]
  unsigned short* Kb = Qb + 8388608;           // [b,h,s,d]
  unsigned short* Vtb = Kb + 8388608;          // [b,h,d,s_perm]
  unsigned short* Ctx = xb;                    // reuse xb (dead after k_gemm_qkv)

  k_cvt<<<12288, 256, 0, stream>>>(x, Wq, Wk, Wv, Wo, xb, Wb);
  k_gemm_qkv<<<dim3(8, 64, 3), 256, 0, stream>>>(xb, Wb, bq, bk, bv, Qb, Kb, Vtb);
  k_flash<<<dim3(16, 64), 256, 0, stream>>>(Qb, Kb, Vtb, Ctx);
  k_gemm_out<<<dim3(8, 64), 256, 0, stream>>>(Ctx, Wb + 3 * 1048576, bo, out);
}

// Round 2
// 320.510 us; speedup vs baseline: 1.1805x; 1.1805x over previous
//
#include <hip/hip_runtime.h>

// SelfAttention: B=4, S=2048, D=1024, H=16, Hd=64. f32 in/out, bf16 MFMA inside.

#define LOG2E 1.4426950408889634f
#define QSCALE (0.125f * LOG2E)   // 1/sqrt(64) * log2(e), folded into Wq/bq

typedef __bf16 bf16x8 __attribute__((ext_vector_type(8)));
typedef float f32x4 __attribute__((ext_vector_type(4)));
typedef unsigned short u16x4 __attribute__((ext_vector_type(4)));
typedef unsigned short u16x8 __attribute__((ext_vector_type(8)));
typedef unsigned int u32x4 __attribute__((ext_vector_type(4)));

__device__ __forceinline__ unsigned short f2bf(float f) {
  unsigned int u = __builtin_bit_cast(unsigned int, f);
  u += 0x7fffu + ((u >> 16) & 1u);   // RNE
  return (unsigned short)(u >> 16);
}

// pack bf16(a) low16, bf16(b) high16; RNE. v_bfe+v_add3 x2 + v_perm.
__device__ __forceinline__ unsigned int pack2bf(float a, float b) {
  unsigned int ua = __builtin_bit_cast(unsigned int, a);
  unsigned int ub = __builtin_bit_cast(unsigned int, b);
  ua += 0x7fffu + ((ua >> 16) & 1u);
  ub += 0x7fffu + ((ub >> 16) & 1u);
  return __builtin_amdgcn_perm(ub, ua, 0x07060302u);
}

typedef const __attribute__((address_space(1))) void* gptr_t;
typedef __attribute__((address_space(3))) void* lptr_t;
__device__ __forceinline__ void gload16(const void* g, void* l) {
  __builtin_amdgcn_global_load_lds((gptr_t)g, (lptr_t)l, 16, 0, 0);
}

// ---------------- merged convert kernel ----------------
__global__ __launch_bounds__(256) void k_cvt(const float* __restrict__ x,
                                             const float* __restrict__ Wq, const float* __restrict__ Wk,
                                             const float* __restrict__ Wv, const float* __restrict__ Wo,
                                             unsigned short* __restrict__ xb, unsigned short* __restrict__ Wb) {
  int gi = (blockIdx.x * 256 + threadIdx.x) * 4;
  if (gi < 8388608) {
    f32x4 v = *(const f32x4*)(x + gi);
    u16x4 o; o[0] = f2bf(v[0]); o[1] = f2bf(v[1]); o[2] = f2bf(v[2]); o[3] = f2bf(v[3]);
    *(u16x4*)(xb + gi) = o;
  } else {
    int i = gi - 8388608;
    int wsel = i >> 20;
    int loc = i & 1048575;
    const float* src = (wsel == 0) ? Wq : (wsel == 1) ? Wk : (wsel == 2) ? Wv : Wo;
    float sc = (wsel == 0) ? QSCALE : 1.0f;
    f32x4 v = *(const f32x4*)(src + loc);
    u16x4 o; o[0] = f2bf(v[0] * sc); o[1] = f2bf(v[1] * sc); o[2] = f2bf(v[2] * sc); o[3] = f2bf(v[3] * sc);
    *(u16x4*)(Wb + i) = o;
  }
}

// ---------------- QKV projection GEMM ----------------
// z=0: Q (pre-scaled) -> [b,h,s,d]; z=1: K -> [b,h,s,d];
// z=2: V -> [b,h,d,s_perm] (pos=8q+4h+r for s=16h+4q+r) so flash PV consumes
//      S^T C-layout regs directly as A-operand fragments.
__global__ __launch_bounds__(256, 2) void k_gemm_qkv(
    const unsigned short* __restrict__ xb, const unsigned short* __restrict__ Wb,
    const float* __restrict__ bq, const float* __restrict__ bk, const float* __restrict__ bv,
    unsigned short* __restrict__ Qb, unsigned short* __restrict__ Kb, unsigned short* __restrict__ Vtb) {
  __shared__ unsigned short As[128 * 32];
  __shared__ unsigned short Bs[128 * 32];
  const int tid = threadIdx.x;
  const int lane = tid & 63;
  const int w = tid >> 6;
  const int wm = w & 1;
  const int wn = w >> 1;
  const int z = blockIdx.z;
  const int m0 = blockIdx.y * 128;
  const int n0 = blockIdx.x * 128;
  const unsigned short* W = Wb + ((size_t)z << 20);

  const int srow = tid >> 2;
  const int sch = (tid & 3) << 3;
  const size_t a0 = (size_t)(m0 + srow) * 1024 + sch;
  const size_t b0 = (size_t)(n0 + srow) * 1024 + sch;

  f32x4 zero4 = {0.f, 0.f, 0.f, 0.f};
  f32x4 acc[4][4];
#pragma unroll
  for (int i = 0; i < 4; ++i)
#pragma unroll
    for (int jj = 0; jj < 4; ++jj) acc[i][jj] = zero4;

  const int fr = lane & 15;
  const int fk = (lane >> 4) << 3;

  for (int kt = 0; kt < 32; ++kt) {
    const int ko = kt << 5;
    __syncthreads();
    gload16(xb + a0 + ko, As + tid * 8);
    gload16(xb + a0 + (size_t)65536 + ko, As + 2048 + tid * 8);
    gload16(W + b0 + ko, Bs + tid * 8);
    gload16(W + b0 + (size_t)65536 + ko, Bs + 2048 + tid * 8);
    __syncthreads();
    bf16x8 af[4], bfr[4];
#pragma unroll
    for (int mt = 0; mt < 4; ++mt)
      af[mt] = *(const bf16x8*)&As[(wm * 64 + mt * 16 + fr) * 32 + fk];
#pragma unroll
    for (int nt = 0; nt < 4; ++nt)
      bfr[nt] = *(const bf16x8*)&Bs[(wn * 64 + nt * 16 + fr) * 32 + fk];
#pragma unroll
    for (int mt = 0; mt < 4; ++mt)
#pragma unroll
      for (int nt = 0; nt < 4; ++nt)
        acc[mt][nt] = __builtin_amdgcn_mfma_f32_16x16x32_bf16(af[mt], bfr[nt], acc[mt][nt], 0, 0, 0);
  }

  const float* bias = (z == 0) ? bq : (z == 1) ? bk : bv;
  const float bsc = (z == 0) ? QSCALE : 1.0f;
  const int rg = (lane >> 4) << 2;
#pragma unroll
  for (int mt = 0; mt < 4; ++mt) {
    const int mb = m0 + wm * 64 + mt * 16 + rg;
    const int b = mb >> 11;
    const int s = mb & 2047;
#pragma unroll
    for (int nt = 0; nt < 4; ++nt) {
      const int n = n0 + wn * 64 + nt * 16 + fr;
      const float bvv = bias[n] * bsc;
      const int h = n >> 6;
      const int d = n & 63;
      if (z == 2) {
        u16x4 pk;
#pragma unroll
        for (int r = 0; r < 4; ++r) pk[r] = f2bf(acc[mt][nt][r] + bvv);
        const int pbase = (s & ~31) | ((s & 12) << 1) | ((s & 16) >> 2);
        *(u16x4*)&Vtb[(((size_t)(b * 16 + h) << 6) + d) * 2048 + pbase] = pk;
      } else {
        unsigned short* O = (z == 0) ? Qb : Kb;
#pragma unroll
        for (int r = 0; r < 4; ++r)
          O[(((size_t)(b * 16 + h) << 11) + s + r) * 64 + d] = f2bf(acc[mt][nt][r] + bvv);
      }
    }
  }
}

// ---------------- flash attention (S^T, no-max softmax, register P, 32q/wave) ----
// r9: r8's pipeline schedule (V_j hidden under QK^T, K_{j+1} double-buffered and
// hidden under the whole iter) but with slimmed addressing registers. r8 spilled
// (WRITE_SIZE 187MB scratch signature, 190us): 32 hoisted LDS offsets + prefetch
// state blew the VGPR cap. Fix: kofs[8][2]->kbase[2] and vofs[4][4]->vbase[4]
// since (kt*16+fr)&7==fr&7 and (dt*16+fr)&15==fr, so the kt*1024 / dt*2048 terms
// are compile-time ds_read offset immediates. Net -26 VGPRs vs r8.
__global__ __launch_bounds__(256, 3) void k_flash(
    const unsigned short* __restrict__ Qb, const unsigned short* __restrict__ Kb,
    const unsigned short* __restrict__ Vtb, unsigned short* __restrict__ Ctx) {
  __shared__ unsigned short Ks[2 * 128 * 64];  // 32KB double-buffered [key][64d], 3-bit chunk xor
  __shared__ unsigned short Vts[64 * 128];     // 16KB [d][128k_perm], 4-bit chunk xor
  const int tid = threadIdx.x;
  const int lane = tid & 63;
  const int wq = tid >> 6;
  const int fr = lane & 15;
  const int qd = lane >> 4;
  const int bh = blockIdx.y;
  const int q0 = blockIdx.x << 7;
  const size_t hoff = (size_t)bh << 17;  // 2048*64
  const unsigned short* Qh = Qb + hoff + ((size_t)q0 << 6);

  // ---- hoisted staging addresses (advance by constant stride per j) ----
  const unsigned short* kg[4];
  const unsigned short* vg[4];
  unsigned short* kl[4];
  unsigned short* vl[4];
#pragma unroll
  for (int p = 0; p < 4; ++p) {
    int slot = p * 256 + tid;
    int kr = slot >> 3, ch = slot & 7;
    kg[p] = Kb + hoff + (size_t)kr * 64 + ((ch ^ (kr & 7)) << 3);
    kl[p] = Ks + slot * 8;
    int dr = slot >> 4, ch2 = slot & 15;
    vg[p] = Vtb + hoff + (size_t)dr * 2048 + ((ch2 ^ (dr & 15)) << 3);
    vl[p] = Vts + slot * 8;
  }

  // ---- slim LDS read base offsets (kt/dt terms fold to ds_read immediates) ----
  int kbase[2];
#pragma unroll
  for (int ds = 0; ds < 2; ++ds)
    kbase[ds] = fr * 64 + (((ds * 4 + qd) ^ (fr & 7)) << 3);
  int vbase[4];
#pragma unroll
  for (int ks = 0; ks < 4; ++ks)
    vbase[ks] = fr * 128 + (((ks * 4 + qd) ^ fr) << 3);

  // Q fragments: B[n=query][k=d]; row = wq*32+qt*16+fr, d = ds*32+qd*8..+7
  bf16x8 qf[2][2];
#pragma unroll
  for (int qt = 0; qt < 2; ++qt)
#pragma unroll
    for (int ds = 0; ds < 2; ++ds)
      qf[qt][ds] = *(const bf16x8*)&Qh[(wq * 32 + qt * 16 + fr) * 64 + ds * 32 + qd * 8];

  f32x4 zero4 = {0.f, 0.f, 0.f, 0.f};
  f32x4 o_acc[2][4];
  float l_p[2] = {0.f, 0.f};
#pragma unroll
  for (int mt = 0; mt < 2; ++mt)
#pragma unroll
    for (int dt = 0; dt < 4; ++dt) o_acc[mt][dt] = zero4;

  // ---- prologue: stage K_0 into buf0, full drain ----
#pragma unroll
  for (int p = 0; p < 4; ++p) gload16(kg[p], kl[p]);
#pragma unroll
  for (int p = 0; p < 4; ++p) kg[p] += 128 * 64;  // -> K_1
  __syncthreads();  // vmcnt(0) + barrier: K_0 visible

  int curoff = 0;  // element offset of current K buffer (0 or 8192)
  for (int j = 0; j < 16; ++j) {
    // invariant at top: K_j visible at Ks+curoff; Vts free (prev PV reads done).
    // Issue V_j (oldest 4, waited by vmcnt(4) after softmax) then K_{j+1}
    // prefetch (waited by vmcnt(0) after PV). Last iter's K_17 prefetch reads
    // the next head's K (or start of Vtb for bh=63) -- valid ws, never consumed.
#pragma unroll
    for (int p = 0; p < 4; ++p) gload16(vg[p], vl[p]);
#pragma unroll
    for (int p = 0; p < 4; ++p) gload16(kg[p], kl[p] + (curoff ^ 8192));
#pragma unroll
    for (int p = 0; p < 4; ++p) { kg[p] += 128 * 64; vg[p] += 128; }

    // ---- S^T = K · Q^T : D[row=key][col=query] (K_j already resident) ----
    const unsigned short* Kc = Ks + curoff;
    f32x4 st[2][8];
#pragma unroll
    for (int qt = 0; qt < 2; ++qt)
#pragma unroll
      for (int kt = 0; kt < 8; ++kt) st[qt][kt] = zero4;
#pragma unroll
    for (int kt = 0; kt < 8; ++kt) {
#pragma unroll
      for (int ds = 0; ds < 2; ++ds) {
        bf16x8 kf = *(const bf16x8*)&Kc[kbase[ds] + kt * 1024];
        st[0][kt] = __builtin_amdgcn_mfma_f32_16x16x32_bf16(kf, qf[0][ds], st[0][kt], 0, 0, 0);
        st[1][kt] = __builtin_amdgcn_mfma_f32_16x16x32_bf16(kf, qf[1][ds], st[1][kt], 0, 0, 0);
      }
    }

    // ---- p = exp2(s) raw; accumulate l in-lane ----
#pragma unroll
    for (int qt = 0; qt < 2; ++qt) {
      float ps0 = 0.f, ps1 = 0.f;
#pragma unroll
      for (int kt = 0; kt < 8; ++kt) {
#pragma unroll
        for (int r = 0; r < 4; ++r) st[qt][kt][r] = __builtin_amdgcn_exp2f(st[qt][kt][r]);
        ps0 += st[qt][kt][0] + st[qt][kt][2];
        ps1 += st[qt][kt][1] + st[qt][kt][3];
      }
      l_p[qt] += ps0 + ps1;
    }

    // V_j done (oldest 4); K_{j+1} may still be in flight
    asm volatile("s_waitcnt vmcnt(4)" ::: "memory");
    __builtin_amdgcn_s_barrier();

    // ---- O += P · V : A-fragments straight from st regs (permuted-key order) ----
#pragma unroll
    for (int ks = 0; ks < 4; ++ks) {
      bf16x8 pf[2];
#pragma unroll
      for (int mt = 0; mt < 2; ++mt) {
        u32x4 pk;
        pk[0] = pack2bf(st[mt][2 * ks][0], st[mt][2 * ks][1]);
        pk[1] = pack2bf(st[mt][2 * ks][2], st[mt][2 * ks][3]);
        pk[2] = pack2bf(st[mt][2 * ks + 1][0], st[mt][2 * ks + 1][1]);
        pk[3] = pack2bf(st[mt][2 * ks + 1][2], st[mt][2 * ks + 1][3]);
        pf[mt] = __builtin_bit_cast(bf16x8, pk);
      }
#pragma unroll
      for (int dt = 0; dt < 4; ++dt) {
        bf16x8 vf = *(const bf16x8*)&Vts[vbase[ks] + dt * 2048];
#pragma unroll
        for (int mt = 0; mt < 2; ++mt)
          o_acc[mt][dt] = __builtin_amdgcn_mfma_f32_16x16x32_bf16(pf[mt], vf, o_acc[mt][dt], 0, 0, 0);
      }
    }

    // K_{j+1} landed; all waves' Vts reads done -> safe to restage next iter
    asm volatile("s_waitcnt vmcnt(0)" ::: "memory");
    __builtin_amdgcn_s_barrier();
    curoff ^= 8192;
  }

  // reduce l across the 4 lanes sharing each query (fr), once
  float l_red[2];
#pragma unroll
  for (int mt = 0; mt < 2; ++mt) {
    float lv = l_p[mt];
    lv += __shfl_xor(lv, 16);
    lv += __shfl_xor(lv, 32);
    l_red[mt] = lv;
  }

  // epilogue: normalize, write context [b][s][h*64+d] bf16
  const int b = bh >> 4;
  const int h = bh & 15;
#pragma unroll
  for (int mt = 0; mt < 2; ++mt) {
#pragma unroll
    for (int r = 0; r < 4; ++r) {
      float lv = __shfl(l_red[mt], qd * 4 + r);
      float rl = 1.0f / lv;
      int s = q0 + wq * 32 + mt * 16 + qd * 4 + r;
      size_t base = (((size_t)b * 2048 + s) << 10) + (h << 6);
#pragma unroll
      for (int dt = 0; dt < 4; ++dt) Ctx[base + dt * 16 + fr] = f2bf(o_acc[mt][dt][r] * rl);
    }
  }
}

// ---------------- output projection GEMM (f32 out) ----------------
__global__ __launch_bounds__(256, 2) void k_gemm_out(
    const unsigned short* __restrict__ Ctx, const unsigned short* __restrict__ Wo,
    const float* __restrict__ bo, float* __restrict__ out) {
  __shared__ unsigned short As[128 * 32];
  __shared__ unsigned short Bs[128 * 32];
  const int tid = threadIdx.x;
  const int lane = tid & 63;
  const int w = tid >> 6;
  const int wm = w & 1;
  const int wn = w >> 1;
  const int m0 = blockIdx.y * 128;
  const int n0 = blockIdx.x * 128;

  const int srow = tid >> 2;
  const int sch = (tid & 3) << 3;
  const size_t a0 = (size_t)(m0 + srow) * 1024 + sch;
  const size_t b0 = (size_t)(n0 + srow) * 1024 + sch;

  f32x4 zero4 = {0.f, 0.f, 0.f, 0.f};
  f32x4 acc[4][4];
#pragma unroll
  for (int i = 0; i < 4; ++i)
#pragma unroll
    for (int jj = 0; jj < 4; ++jj) acc[i][jj] = zero4;

  const int fr = lane & 15;
  const int fk = (lane >> 4) << 3;

  for (int kt = 0; kt < 32; ++kt) {
    const int ko = kt << 5;
    __syncthreads();
    gload16(Ctx + a0 + ko, As + tid * 8);
    gload16(Ctx + a0 + (size_t)65536 + ko, As + 2048 + tid * 8);
    gload16(Wo + b0 + ko, Bs + tid * 8);
    gload16(Wo + b0 + (size_t)65536 + ko, Bs + 2048 + tid * 8);
    __syncthreads();
    bf16x8 af[4], bfr[4];
#pragma unroll
    for (int mt = 0; mt < 4; ++mt)
      af[mt] = *(const bf16x8*)&As[(wm * 64 + mt * 16 + fr) * 32 + fk];
#pragma unroll
    for (int nt = 0; nt < 4; ++nt)
      bfr[nt] = *(const bf16x8*)&Bs[(wn * 64 + nt * 16 + fr) * 32 + fk];
#pragma unroll
    for (int mt = 0; mt < 4; ++mt)
#pragma unroll
      for (int nt = 0; nt < 4; ++nt)
        acc[mt][nt] = __builtin_amdgcn_mfma_f32_16x16x32_bf16(af[mt], bfr[nt], acc[mt][nt], 0, 0, 0);
  }

  const int rg = (lane >> 4) << 2;
#pragma unroll
  for (int mt = 0; mt < 4; ++mt) {
    const int mb = m0 + wm * 64 + mt * 16 + rg;
#pragma unroll
    for (int nt = 0; nt < 4; ++nt) {
      const int n = n0 + wn * 64 + nt * 16 + fr;
      const float bvv = bo[n];
#pragma unroll
      for (int r = 0; r < 4; ++r)
        out[(size_t)(mb + r) * 1024 + n] = acc[mt][nt][r] + bvv;
    }
  }
}

// ---------------- host ----------------
extern "C" void kernel_launch(void* const* d_in, const int* in_sizes, int n_in,
                              void* d_out, int out_size, void* d_ws, size_t ws_size,
                              hipStream_t stream) {
  (void)in_sizes; (void)n_in; (void)out_size; (void)ws_size;
  const float* x = (const float*)d_in[0];
  const float* Wq = (const float*)d_in[1];
  const float* bq = (const float*)d_in[2];
  const float* Wk = (const float*)d_in[3];
  const float* bk = (const float*)d_in[4];
  const float* Wv = (const float*)d_in[5];
  const float* bv = (const float*)d_in[6];
  const float* Wo = (const float*)d_in[7];
  const float* bo = (const float*)d_in[8];
  float* out = (float*)d_out;

  unsigned short* xb = (unsigned short*)d_ws;  // 8388608 el
  unsigned short* Wb = xb + 8388608;           // 4194304 el (q,k,v,o)
  unsigned short* Qb = Wb + 4194304;           // [b,h,s,d]
  unsigned short* Kb = Qb + 8388608;           // [b,h,s,d]
  unsigned short* Vtb = Kb + 8388608;          // [b,h,d,s_perm]
  unsigned short* Ctx = xb;                    // reuse xb (dead after k_gemm_qkv)

  k_cvt<<<12288, 256, 0, stream>>>(x, Wq, Wk, Wv, Wo, xb, Wb);
  k_gemm_qkv<<<dim3(8, 64, 3), 256, 0, stream>>>(xb, Wb, bq, bk, bv, Qb, Kb, Vtb);
  k_flash<<<dim3(16, 64), 256, 0, stream>>>(Qb, Kb, Vtb, Ctx);
  k_gemm_out<<<dim3(8, 64), 256, 0, stream>>>(Ctx, Wb + 3 * 1048576, bo, out);
}

// Round 3
// 288.656 us; speedup vs baseline: 1.3108x; 1.1104x over previous
//
#include <hip/hip_runtime.h>

// SelfAttention: B=4, S=2048, D=1024, H=16, Hd=64. f32 in/out, bf16 MFMA inside.

#define LOG2E 1.4426950408889634f
#define QSCALE (0.125f * LOG2E)   // 1/sqrt(64) * log2(e), folded into Wq/bq

typedef __bf16 bf16x8 __attribute__((ext_vector_type(8)));
typedef float f32x4 __attribute__((ext_vector_type(4)));
typedef unsigned short u16x4 __attribute__((ext_vector_type(4)));
typedef unsigned short u16x8 __attribute__((ext_vector_type(8)));
typedef unsigned int u32x4 __attribute__((ext_vector_type(4)));

__device__ __forceinline__ unsigned short f2bf(float f) {
  unsigned int u = __builtin_bit_cast(unsigned int, f);
  u += 0x7fffu + ((u >> 16) & 1u);   // RNE
  return (unsigned short)(u >> 16);
}

// pack bf16(a) low16, bf16(b) high16; RNE. v_bfe+v_add3 x2 + v_perm.
__device__ __forceinline__ unsigned int pack2bf(float a, float b) {
  unsigned int ua = __builtin_bit_cast(unsigned int, a);
  unsigned int ub = __builtin_bit_cast(unsigned int, b);
  ua += 0x7fffu + ((ua >> 16) & 1u);
  ub += 0x7fffu + ((ub >> 16) & 1u);
  return __builtin_amdgcn_perm(ub, ua, 0x07060302u);
}

typedef const __attribute__((address_space(1))) void* gptr_t;
typedef __attribute__((address_space(3))) void* lptr_t;
__device__ __forceinline__ void gload16(const void* g, void* l) {
  __builtin_amdgcn_global_load_lds((gptr_t)g, (lptr_t)l, 16, 0, 0);
}

// ---------------- merged convert kernel ----------------
__global__ __launch_bounds__(256) void k_cvt(const float* __restrict__ x,
                                             const float* __restrict__ Wq, const float* __restrict__ Wk,
                                             const float* __restrict__ Wv, const float* __restrict__ Wo,
                                             unsigned short* __restrict__ xb, unsigned short* __restrict__ Wb) {
  int gi = (blockIdx.x * 256 + threadIdx.x) * 4;
  if (gi < 8388608) {
    f32x4 v = *(const f32x4*)(x + gi);
    u16x4 o; o[0] = f2bf(v[0]); o[1] = f2bf(v[1]); o[2] = f2bf(v[2]); o[3] = f2bf(v[3]);
    *(u16x4*)(xb + gi) = o;
  } else {
    int i = gi - 8388608;
    int wsel = i >> 20;
    int loc = i & 1048575;
    const float* src = (wsel == 0) ? Wq : (wsel == 1) ? Wk : (wsel == 2) ? Wv : Wo;
    float sc = (wsel == 0) ? QSCALE : 1.0f;
    f32x4 v = *(const f32x4*)(src + loc);
    u16x4 o; o[0] = f2bf(v[0] * sc); o[1] = f2bf(v[1] * sc); o[2] = f2bf(v[2] * sc); o[3] = f2bf(v[3] * sc);
    *(u16x4*)(Wb + i) = o;
  }
}

// ---------------- QKV projection GEMM ----------------
// z=0: Q (pre-scaled) -> [b,h,s,d]; z=1: K -> [b,h,s,d];
// z=2: V -> [b,h,d,s_perm] (pos=8q+4h+r for s=16h+4q+r) so flash PV consumes
//      S^T C-layout regs directly as A-operand fragments.
__global__ __launch_bounds__(256, 2) void k_gemm_qkv(
    const unsigned short* __restrict__ xb, const unsigned short* __restrict__ Wb,
    const float* __restrict__ bq, const float* __restrict__ bk, const float* __restrict__ bv,
    unsigned short* __restrict__ Qb, unsigned short* __restrict__ Kb, unsigned short* __restrict__ Vtb) {
  __shared__ unsigned short As[128 * 32];
  __shared__ unsigned short Bs[128 * 32];
  const int tid = threadIdx.x;
  const int lane = tid & 63;
  const int w = tid >> 6;
  const int wm = w & 1;
  const int wn = w >> 1;
  const int z = blockIdx.z;
  const int m0 = blockIdx.y * 128;
  const int n0 = blockIdx.x * 128;
  const unsigned short* W = Wb + ((size_t)z << 20);

  const int srow = tid >> 2;
  const int sch = (tid & 3) << 3;
  const size_t a0 = (size_t)(m0 + srow) * 1024 + sch;
  const size_t b0 = (size_t)(n0 + srow) * 1024 + sch;

  f32x4 zero4 = {0.f, 0.f, 0.f, 0.f};
  f32x4 acc[4][4];
#pragma unroll
  for (int i = 0; i < 4; ++i)
#pragma unroll
    for (int jj = 0; jj < 4; ++jj) acc[i][jj] = zero4;

  const int fr = lane & 15;
  const int fk = (lane >> 4) << 3;

  for (int kt = 0; kt < 32; ++kt) {
    const int ko = kt << 5;
    __syncthreads();
    gload16(xb + a0 + ko, As + tid * 8);
    gload16(xb + a0 + (size_t)65536 + ko, As + 2048 + tid * 8);
    gload16(W + b0 + ko, Bs + tid * 8);
    gload16(W + b0 + (size_t)65536 + ko, Bs + 2048 + tid * 8);
    __syncthreads();
    bf16x8 af[4], bfr[4];
#pragma unroll
    for (int mt = 0; mt < 4; ++mt)
      af[mt] = *(const bf16x8*)&As[(wm * 64 + mt * 16 + fr) * 32 + fk];
#pragma unroll
    for (int nt = 0; nt < 4; ++nt)
      bfr[nt] = *(const bf16x8*)&Bs[(wn * 64 + nt * 16 + fr) * 32 + fk];
#pragma unroll
    for (int mt = 0; mt < 4; ++mt)
#pragma unroll
      for (int nt = 0; nt < 4; ++nt)
        acc[mt][nt] = __builtin_amdgcn_mfma_f32_16x16x32_bf16(af[mt], bfr[nt], acc[mt][nt], 0, 0, 0);
  }

  const float* bias = (z == 0) ? bq : (z == 1) ? bk : bv;
  const float bsc = (z == 0) ? QSCALE : 1.0f;
  const int rg = (lane >> 4) << 2;
#pragma unroll
  for (int mt = 0; mt < 4; ++mt) {
    const int mb = m0 + wm * 64 + mt * 16 + rg;
    const int b = mb >> 11;
    const int s = mb & 2047;
#pragma unroll
    for (int nt = 0; nt < 4; ++nt) {
      const int n = n0 + wn * 64 + nt * 16 + fr;
      const float bvv = bias[n] * bsc;
      const int h = n >> 6;
      const int d = n & 63;
      if (z == 2) {
        u16x4 pk;
#pragma unroll
        for (int r = 0; r < 4; ++r) pk[r] = f2bf(acc[mt][nt][r] + bvv);
        const int pbase = (s & ~31) | ((s & 12) << 1) | ((s & 16) >> 2);
        *(u16x4*)&Vtb[(((size_t)(b * 16 + h) << 6) + d) * 2048 + pbase] = pk;
      } else {
        unsigned short* O = (z == 0) ? Qb : Kb;
#pragma unroll
        for (int r = 0; r < 4; ++r)
          O[(((size_t)(b * 16 + h) << 11) + s + r) * 64 + d] = f2bf(acc[mt][nt][r] + bvv);
      }
    }
  }
}

// ---------------- flash attention (S^T, no-max softmax, register P, 32q/wave) ----
// r10: r9 still spilled (WRITE 64MB vs 16 legit; VGPR cap 168 at 3 waves/EU).
// Root cause: st[2][8] held the full 32q x 128k f32 score tile (64 VGPRs) live
// across separate exp/sum/pack loops. Fix: fuse exp + l-sum + bf16 pack into the
// QK^T loop per key-pair (ks = kt/2). Live state: pfw[2][4] packed bf16 (32
// regs) + 16 transient, peak ~145 regs -> no spill. Pipeline schedule (V_j
// hidden under QK^T via vmcnt(4); K_{j+1} double-buffered, vmcnt(0) at iter
// end) is unchanged from r9.
__global__ __launch_bounds__(256, 3) void k_flash(
    const unsigned short* __restrict__ Qb, const unsigned short* __restrict__ Kb,
    const unsigned short* __restrict__ Vtb, unsigned short* __restrict__ Ctx) {
  __shared__ unsigned short Ks[2 * 128 * 64];  // 32KB double-buffered [key][64d], 3-bit chunk xor
  __shared__ unsigned short Vts[64 * 128];     // 16KB [d][128k_perm], 4-bit chunk xor
  const int tid = threadIdx.x;
  const int lane = tid & 63;
  const int wq = tid >> 6;
  const int fr = lane & 15;
  const int qd = lane >> 4;
  const int bh = blockIdx.y;
  const int q0 = blockIdx.x << 7;
  const size_t hoff = (size_t)bh << 17;  // 2048*64
  const unsigned short* Qh = Qb + hoff + ((size_t)q0 << 6);

  // ---- hoisted staging addresses (advance by constant stride per j) ----
  const unsigned short* kg[4];
  const unsigned short* vg[4];
  unsigned short* kl[4];
  unsigned short* vl[4];
#pragma unroll
  for (int p = 0; p < 4; ++p) {
    int slot = p * 256 + tid;
    int kr = slot >> 3, ch = slot & 7;
    kg[p] = Kb + hoff + (size_t)kr * 64 + ((ch ^ (kr & 7)) << 3);
    kl[p] = Ks + slot * 8;
    int dr = slot >> 4, ch2 = slot & 15;
    vg[p] = Vtb + hoff + (size_t)dr * 2048 + ((ch2 ^ (dr & 15)) << 3);
    vl[p] = Vts + slot * 8;
  }

  // ---- slim LDS read base offsets (kt/dt terms fold to ds_read immediates) ----
  int kbase[2];
#pragma unroll
  for (int ds = 0; ds < 2; ++ds)
    kbase[ds] = fr * 64 + (((ds * 4 + qd) ^ (fr & 7)) << 3);
  int vbase[4];
#pragma unroll
  for (int ks = 0; ks < 4; ++ks)
    vbase[ks] = fr * 128 + (((ks * 4 + qd) ^ fr) << 3);

  // Q fragments: B[n=query][k=d]; row = wq*32+qt*16+fr, d = ds*32+qd*8..+7
  bf16x8 qf[2][2];
#pragma unroll
  for (int qt = 0; qt < 2; ++qt)
#pragma unroll
    for (int ds = 0; ds < 2; ++ds)
      qf[qt][ds] = *(const bf16x8*)&Qh[(wq * 32 + qt * 16 + fr) * 64 + ds * 32 + qd * 8];

  f32x4 zero4 = {0.f, 0.f, 0.f, 0.f};
  f32x4 o_acc[2][4];
  float l_p[2] = {0.f, 0.f};
#pragma unroll
  for (int mt = 0; mt < 2; ++mt)
#pragma unroll
    for (int dt = 0; dt < 4; ++dt) o_acc[mt][dt] = zero4;

  // ---- prologue: stage K_0 into buf0, full drain ----
#pragma unroll
  for (int p = 0; p < 4; ++p) gload16(kg[p], kl[p]);
#pragma unroll
  for (int p = 0; p < 4; ++p) kg[p] += 128 * 64;  // -> K_1
  __syncthreads();  // vmcnt(0) + barrier: K_0 visible

  int curoff = 0;  // element offset of current K buffer (0 or 8192)
  for (int j = 0; j < 16; ++j) {
    // invariant at top: K_j visible at Ks+curoff; Vts free (prev PV reads done).
    // Issue V_j (oldest 4, waited by vmcnt(4) after softmax) then K_{j+1}
    // prefetch (waited by vmcnt(0) after PV). Last iter's K_17 prefetch reads
    // the next head's K (or start of Vtb for bh=63) -- valid ws, never consumed.
#pragma unroll
    for (int p = 0; p < 4; ++p) gload16(vg[p], vl[p]);
#pragma unroll
    for (int p = 0; p < 4; ++p) gload16(kg[p], kl[p] + (curoff ^ 8192));
#pragma unroll
    for (int p = 0; p < 4; ++p) { kg[p] += 128 * 64; vg[p] += 128; }

    // ---- fused S^T = K·Q^T -> exp2 -> l-sum -> bf16 pack, per key-pair ----
    // st[qt][kt] is final after its kt MFMAs; consume immediately so only the
    // packed bf16 fragments pfw[2][4] (32 regs) stay live, not st[2][8] (64).
    const unsigned short* Kc = Ks + curoff;
    u32x4 pfw[2][4];
#pragma unroll
    for (int ks = 0; ks < 4; ++ks) {
      f32x4 st0[2], st1[2];  // [qt] for kt=2ks, 2ks+1
      st0[0] = zero4; st0[1] = zero4; st1[0] = zero4; st1[1] = zero4;
#pragma unroll
      for (int ds = 0; ds < 2; ++ds) {
        bf16x8 kf0 = *(const bf16x8*)&Kc[kbase[ds] + (2 * ks) * 1024];
        bf16x8 kf1 = *(const bf16x8*)&Kc[kbase[ds] + (2 * ks + 1) * 1024];
        st0[0] = __builtin_amdgcn_mfma_f32_16x16x32_bf16(kf0, qf[0][ds], st0[0], 0, 0, 0);
        st0[1] = __builtin_amdgcn_mfma_f32_16x16x32_bf16(kf0, qf[1][ds], st0[1], 0, 0, 0);
        st1[0] = __builtin_amdgcn_mfma_f32_16x16x32_bf16(kf1, qf[0][ds], st1[0], 0, 0, 0);
        st1[1] = __builtin_amdgcn_mfma_f32_16x16x32_bf16(kf1, qf[1][ds], st1[1], 0, 0, 0);
      }
#pragma unroll
      for (int mt = 0; mt < 2; ++mt) {
#pragma unroll
        for (int r = 0; r < 4; ++r) {
          st0[mt][r] = __builtin_amdgcn_exp2f(st0[mt][r]);
          st1[mt][r] = __builtin_amdgcn_exp2f(st1[mt][r]);
        }
        l_p[mt] += ((st0[mt][0] + st0[mt][1]) + (st0[mt][2] + st0[mt][3])) +
                   ((st1[mt][0] + st1[mt][1]) + (st1[mt][2] + st1[mt][3]));
        u32x4 pk;
        pk[0] = pack2bf(st0[mt][0], st0[mt][1]);
        pk[1] = pack2bf(st0[mt][2], st0[mt][3]);
        pk[2] = pack2bf(st1[mt][0], st1[mt][1]);
        pk[3] = pack2bf(st1[mt][2], st1[mt][3]);
        pfw[mt][ks] = pk;
      }
    }

    // V_j done (oldest 4); K_{j+1} may still be in flight
    asm volatile("s_waitcnt vmcnt(4)" ::: "memory");
    __builtin_amdgcn_s_barrier();

    // ---- O += P · V : A-fragments from packed regs (permuted-key order) ----
#pragma unroll
    for (int ks = 0; ks < 4; ++ks) {
      bf16x8 pf0 = __builtin_bit_cast(bf16x8, pfw[0][ks]);
      bf16x8 pf1 = __builtin_bit_cast(bf16x8, pfw[1][ks]);
#pragma unroll
      for (int dt = 0; dt < 4; ++dt) {
        bf16x8 vf = *(const bf16x8*)&Vts[vbase[ks] + dt * 2048];
        o_acc[0][dt] = __builtin_amdgcn_mfma_f32_16x16x32_bf16(pf0, vf, o_acc[0][dt], 0, 0, 0);
        o_acc[1][dt] = __builtin_amdgcn_mfma_f32_16x16x32_bf16(pf1, vf, o_acc[1][dt], 0, 0, 0);
      }
    }

    // K_{j+1} landed; all waves' Vts reads done -> safe to restage next iter
    asm volatile("s_waitcnt vmcnt(0)" ::: "memory");
    __builtin_amdgcn_s_barrier();
    curoff ^= 8192;
  }

  // reduce l across the 4 lanes sharing each query (fr), once
  float l_red[2];
#pragma unroll
  for (int mt = 0; mt < 2; ++mt) {
    float lv = l_p[mt];
    lv += __shfl_xor(lv, 16);
    lv += __shfl_xor(lv, 32);
    l_red[mt] = lv;
  }

  // epilogue: normalize, write context [b][s][h*64+d] bf16
  const int b = bh >> 4;
  const int h = bh & 15;
#pragma unroll
  for (int mt = 0; mt < 2; ++mt) {
#pragma unroll
    for (int r = 0; r < 4; ++r) {
      float lv = __shfl(l_red[mt], qd * 4 + r);
      float rl = 1.0f / lv;
      int s = q0 + wq * 32 + mt * 16 + qd * 4 + r;
      size_t base = (((size_t)b * 2048 + s) << 10) + (h << 6);
#pragma unroll
      for (int dt = 0; dt < 4; ++dt) Ctx[base + dt * 16 + fr] = f2bf(o_acc[mt][dt][r] * rl);
    }
  }
}

// ---------------- output projection GEMM (f32 out) ----------------
__global__ __launch_bounds__(256, 2) void k_gemm_out(
    const unsigned short* __restrict__ Ctx, const unsigned short* __restrict__ Wo,
    const float* __restrict__ bo, float* __restrict__ out) {
  __shared__ unsigned short As[128 * 32];
  __shared__ unsigned short Bs[128 * 32];
  const int tid = threadIdx.x;
  const int lane = tid & 63;
  const int w = tid >> 6;
  const int wm = w & 1;
  const int wn = w >> 1;
  const int m0 = blockIdx.y * 128;
  const int n0 = blockIdx.x * 128;

  const int srow = tid >> 2;
  const int sch = (tid & 3) << 3;
  const size_t a0 = (size_t)(m0 + srow) * 1024 + sch;
  const size_t b0 = (size_t)(n0 + srow) * 1024 + sch;

  f32x4 zero4 = {0.f, 0.f, 0.f, 0.f};
  f32x4 acc[4][4];
#pragma unroll
  for (int i = 0; i < 4; ++i)
#pragma unroll
    for (int jj = 0; jj < 4; ++jj) acc[i][jj] = zero4;

  const int fr = lane & 15;
  const int fk = (lane >> 4) << 3;

  for (int kt = 0; kt < 32; ++kt) {
    const int ko = kt << 5;
    __syncthreads();
    gload16(Ctx + a0 + ko, As + tid * 8);
    gload16(Ctx + a0 + (size_t)65536 + ko, As + 2048 + tid * 8);
    gload16(Wo + b0 + ko, Bs + tid * 8);
    gload16(Wo + b0 + (size_t)65536 + ko, Bs + 2048 + tid * 8);
    __syncthreads();
    bf16x8 af[4], bfr[4];
#pragma unroll
    for (int mt = 0; mt < 4; ++mt)
      af[mt] = *(const bf16x8*)&As[(wm * 64 + mt * 16 + fr) * 32 + fk];
#pragma unroll
    for (int nt = 0; nt < 4; ++nt)
      bfr[nt] = *(const bf16x8*)&Bs[(wn * 64 + nt * 16 + fr) * 32 + fk];
#pragma unroll
    for (int mt = 0; mt < 4; ++mt)
#pragma unroll
      for (int nt = 0; nt < 4; ++nt)
        acc[mt][nt] = __builtin_amdgcn_mfma_f32_16x16x32_bf16(af[mt], bfr[nt], acc[mt][nt], 0, 0, 0);
  }

  const int rg = (lane >> 4) << 2;
#pragma unroll
  for (int mt = 0; mt < 4; ++mt) {
    const int mb = m0 + wm * 64 + mt * 16 + rg;
#pragma unroll
    for (int nt = 0; nt < 4; ++nt) {
      const int n = n0 + wn * 64 + nt * 16 + fr;
      const float bvv = bo[n];
#pragma unroll
      for (int r = 0; r < 4; ++r)
        out[(size_t)(mb + r) * 1024 + n] = acc[mt][nt][r] + bvv;
    }
  }
}

// ---------------- host ----------------
extern "C" void kernel_launch(void* const* d_in, const int* in_sizes, int n_in,
                              void* d_out, int out_size, void* d_ws, size_t ws_size,
                              hipStream_t stream) {
  (void)in_sizes; (void)n_in; (void)out_size; (void)ws_size;
  const float* x = (const float*)d_in[0];
  const float* Wq = (const float*)d_in[1];
  const float* bq = (const float*)d_in[2];
  const float* Wk = (const float*)d_in[3];
  const float* bk = (const float*)d_in[4];
  const float* Wv = (const float*)d_in[5];
  const float* bv = (const float*)d_in[6];
  const float* Wo = (const float*)d_in[7];
  const float* bo = (const float*)d_in[8];
  float* out = (float*)d_out;

  unsigned short* xb = (unsigned short*)d_ws;  // 8388608 el
  unsigned short* Wb = xb + 8388608;           // 4194304 el (q,k,v,o)
  unsigned short* Qb = Wb + 4194304;           // [b,h,s,d]
  unsigned short* Kb = Qb + 8388608;           // [b,h,s,d]
  unsigned short* Vtb = Kb + 8388608;          // [b,h,d,s_perm]
  unsigned short* Ctx = xb;                    // reuse xb (dead after k_gemm_qkv)

  k_cvt<<<12288, 256, 0, stream>>>(x, Wq, Wk, Wv, Wo, xb, Wb);
  k_gemm_qkv<<<dim3(8, 64, 3), 256, 0, stream>>>(xb, Wb, bq, bk, bv, Qb, Kb, Vtb);
  k_flash<<<dim3(16, 64), 256, 0, stream>>>(Qb, Kb, Vtb, Ctx);
  k_gemm_out<<<dim3(8, 64), 256, 0, stream>>>(Ctx, Wb + 3 * 1048576, bo, out);
}

// Round 4
// 273.257 us; speedup vs baseline: 1.3847x; 1.0564x over previous
//
#include <hip/hip_runtime.h>

// SelfAttention: B=4, S=2048, D=1024, H=16, Hd=64. f32 in/out, bf16 MFMA inside.

#define LOG2E 1.4426950408889634f
#define QSCALE (0.125f * LOG2E)   // 1/sqrt(64) * log2(e), folded into Wq/bq

typedef __bf16 bf16x8 __attribute__((ext_vector_type(8)));
typedef float f32x4 __attribute__((ext_vector_type(4)));
typedef float f32x2 __attribute__((ext_vector_type(2)));
typedef unsigned short u16x4 __attribute__((ext_vector_type(4)));
typedef unsigned short u16x8 __attribute__((ext_vector_type(8)));
typedef unsigned int u32x4 __attribute__((ext_vector_type(4)));

__device__ __forceinline__ unsigned short f2bf(float f) {
  unsigned int u = __builtin_bit_cast(unsigned int, f);
  u += 0x7fffu + ((u >> 16) & 1u);   // RNE
  return (unsigned short)(u >> 16);
}

// single-instruction pack: bf16(a) low16, bf16(b) high16 (RNE). gfx950 only.
__device__ __forceinline__ unsigned int cvtpk(float a, float b) {
  unsigned int r;
  asm("v_cvt_pk_bf16_f32 %0, %1, %2" : "=v"(r) : "v"(a), "v"(b));
  return r;
}

typedef const __attribute__((address_space(1))) void* gptr_t;
typedef __attribute__((address_space(3))) void* lptr_t;
__device__ __forceinline__ void gload16(const void* g, void* l) {
  __builtin_amdgcn_global_load_lds((gptr_t)g, (lptr_t)l, 16, 0, 0);
}

// ---------------- merged convert kernel ----------------
__global__ __launch_bounds__(256) void k_cvt(const float* __restrict__ x,
                                             const float* __restrict__ Wq, const float* __restrict__ Wk,
                                             const float* __restrict__ Wv, const float* __restrict__ Wo,
                                             unsigned short* __restrict__ xb, unsigned short* __restrict__ Wb) {
  int gi = (blockIdx.x * 256 + threadIdx.x) * 4;
  if (gi < 8388608) {
    f32x4 v = *(const f32x4*)(x + gi);
    u16x4 o; o[0] = f2bf(v[0]); o[1] = f2bf(v[1]); o[2] = f2bf(v[2]); o[3] = f2bf(v[3]);
    *(u16x4*)(xb + gi) = o;
  } else {
    int i = gi - 8388608;
    int wsel = i >> 20;
    int loc = i & 1048575;
    const float* src = (wsel == 0) ? Wq : (wsel == 1) ? Wk : (wsel == 2) ? Wv : Wo;
    float sc = (wsel == 0) ? QSCALE : 1.0f;
    f32x4 v = *(const f32x4*)(src + loc);
    u16x4 o; o[0] = f2bf(v[0] * sc); o[1] = f2bf(v[1] * sc); o[2] = f2bf(v[2] * sc); o[3] = f2bf(v[3] * sc);
    *(u16x4*)(Wb + i) = o;
  }
}

// ---------------- QKV projection GEMM ----------------
// z=0: Q (pre-scaled) -> [b,h,s,d]; z=1: K -> [b,h,s,d];
// z=2: V -> [b,h,d,s_perm] (pos=8q+4h+r for s=16h+4q+r) so flash PV consumes
//      S^T C-layout regs directly as A-operand fragments.
// r11: XCD-chunked tile swizzle (nwg=1536, chunk=192): each XCD's L2 sees
// contiguous tiles (n fastest) -> A-panel (128 rows of x) reused 8x in-L2
// instead of fetched by 8 XCDs.
__global__ __launch_bounds__(256, 2) void k_gemm_qkv(
    const unsigned short* __restrict__ xb, const unsigned short* __restrict__ Wb,
    const float* __restrict__ bq, const float* __restrict__ bk, const float* __restrict__ bv,
    unsigned short* __restrict__ Qb, unsigned short* __restrict__ Kb, unsigned short* __restrict__ Vtb) {
  __shared__ unsigned short As[128 * 32];
  __shared__ unsigned short Bs[128 * 32];
  const int tid = threadIdx.x;
  const int lane = tid & 63;
  const int w = tid >> 6;
  const int wm = w & 1;
  const int wn = w >> 1;
  const int lin = blockIdx.x + (blockIdx.y << 3) + (blockIdx.z << 9);
  const int swz = (lin & 7) * 192 + (lin >> 3);
  const int z = swz >> 9;
  const int m0 = ((swz >> 3) & 63) << 7;
  const int n0 = (swz & 7) << 7;
  const unsigned short* W = Wb + ((size_t)z << 20);

  const int srow = tid >> 2;
  const int sch = (tid & 3) << 3;
  const size_t a0 = (size_t)(m0 + srow) * 1024 + sch;
  const size_t b0 = (size_t)(n0 + srow) * 1024 + sch;

  f32x4 zero4 = {0.f, 0.f, 0.f, 0.f};
  f32x4 acc[4][4];
#pragma unroll
  for (int i = 0; i < 4; ++i)
#pragma unroll
    for (int jj = 0; jj < 4; ++jj) acc[i][jj] = zero4;

  const int fr = lane & 15;
  const int fk = (lane >> 4) << 3;

  for (int kt = 0; kt < 32; ++kt) {
    const int ko = kt << 5;
    __syncthreads();
    gload16(xb + a0 + ko, As + tid * 8);
    gload16(xb + a0 + (size_t)65536 + ko, As + 2048 + tid * 8);
    gload16(W + b0 + ko, Bs + tid * 8);
    gload16(W + b0 + (size_t)65536 + ko, Bs + 2048 + tid * 8);
    __syncthreads();
    bf16x8 af[4], bfr[4];
#pragma unroll
    for (int mt = 0; mt < 4; ++mt)
      af[mt] = *(const bf16x8*)&As[(wm * 64 + mt * 16 + fr) * 32 + fk];
#pragma unroll
    for (int nt = 0; nt < 4; ++nt)
      bfr[nt] = *(const bf16x8*)&Bs[(wn * 64 + nt * 16 + fr) * 32 + fk];
#pragma unroll
    for (int mt = 0; mt < 4; ++mt)
#pragma unroll
      for (int nt = 0; nt < 4; ++nt)
        acc[mt][nt] = __builtin_amdgcn_mfma_f32_16x16x32_bf16(af[mt], bfr[nt], acc[mt][nt], 0, 0, 0);
  }

  const float* bias = (z == 0) ? bq : (z == 1) ? bk : bv;
  const float bsc = (z == 0) ? QSCALE : 1.0f;
  const int rg = (lane >> 4) << 2;
#pragma unroll
  for (int mt = 0; mt < 4; ++mt) {
    const int mb = m0 + wm * 64 + mt * 16 + rg;
    const int b = mb >> 11;
    const int s = mb & 2047;
#pragma unroll
    for (int nt = 0; nt < 4; ++nt) {
      const int n = n0 + wn * 64 + nt * 16 + fr;
      const float bvv = bias[n] * bsc;
      const int h = n >> 6;
      const int d = n & 63;
      if (z == 2) {
        u16x4 pk;
#pragma unroll
        for (int r = 0; r < 4; ++r) pk[r] = f2bf(acc[mt][nt][r] + bvv);
        const int pbase = (s & ~31) | ((s & 12) << 1) | ((s & 16) >> 2);
        *(u16x4*)&Vtb[(((size_t)(b * 16 + h) << 6) + d) * 2048 + pbase] = pk;
      } else {
        unsigned short* O = (z == 0) ? Qb : Kb;
#pragma unroll
        for (int r = 0; r < 4; ++r)
          O[(((size_t)(b * 16 + h) << 11) + s + r) * 64 + d] = f2bf(acc[mt][nt][r] + bvv);
      }
    }
  }
}

// ---------------- flash attention (S^T, no-max softmax, register P, 32q/wave) ----
// r11 (on r10's no-spill fused structure):
//  (a) XCD-chunked tile swizzle (nwg=1024, chunk=128): each XCD owns 8 complete
//      heads -> K/V fetched once into that XCD's L2 (resident set ~3MB < 4MB)
//      instead of 3-4x from HBM (FETCH was 143MB vs 48MB unique). Shortens the
//      vmcnt(4) V-wait (L2 ~200cy vs HBM ~900cy).
//  (b) pack2bf (5 VALU ops) -> v_cvt_pk_bf16_f32 (1 op), 16/iter: -64 VALU/iter.
//  (c) l-sum paired into float2 adds (v_pk_add_f32): 64 -> 32 VALU/iter.
// Pipeline schedule (V_j under QK^T via vmcnt(4); K_{j+1} dbuf, vmcnt(0) at
// iter end) unchanged from r9/r10.
__global__ __launch_bounds__(256, 3) void k_flash(
    const unsigned short* __restrict__ Qb, const unsigned short* __restrict__ Kb,
    const unsigned short* __restrict__ Vtb, unsigned short* __restrict__ Ctx) {
  __shared__ unsigned short Ks[2 * 128 * 64];  // 32KB double-buffered [key][64d], 3-bit chunk xor
  __shared__ unsigned short Vts[64 * 128];     // 16KB [d][128k_perm], 4-bit chunk xor
  const int tid = threadIdx.x;
  const int lane = tid & 63;
  const int wq = tid >> 6;
  const int fr = lane & 15;
  const int qd = lane >> 4;
  const int lin = blockIdx.x + (blockIdx.y << 4);
  const int swz = ((lin & 7) << 7) + (lin >> 3);
  const int bh = swz >> 4;
  const int q0 = (swz & 15) << 7;
  const size_t hoff = (size_t)bh << 17;  // 2048*64
  const unsigned short* Qh = Qb + hoff + ((size_t)q0 << 6);

  // ---- hoisted staging addresses (advance by constant stride per j) ----
  const unsigned short* kg[4];
  const unsigned short* vg[4];
  unsigned short* kl[4];
  unsigned short* vl[4];
#pragma unroll
  for (int p = 0; p < 4; ++p) {
    int slot = p * 256 + tid;
    int kr = slot >> 3, ch = slot & 7;
    kg[p] = Kb + hoff + (size_t)kr * 64 + ((ch ^ (kr & 7)) << 3);
    kl[p] = Ks + slot * 8;
    int dr = slot >> 4, ch2 = slot & 15;
    vg[p] = Vtb + hoff + (size_t)dr * 2048 + ((ch2 ^ (dr & 15)) << 3);
    vl[p] = Vts + slot * 8;
  }

  // ---- slim LDS read base offsets (kt/dt terms fold to ds_read immediates) ----
  int kbase[2];
#pragma unroll
  for (int ds = 0; ds < 2; ++ds)
    kbase[ds] = fr * 64 + (((ds * 4 + qd) ^ (fr & 7)) << 3);
  int vbase[4];
#pragma unroll
  for (int ks = 0; ks < 4; ++ks)
    vbase[ks] = fr * 128 + (((ks * 4 + qd) ^ fr) << 3);

  // Q fragments: B[n=query][k=d]; row = wq*32+qt*16+fr, d = ds*32+qd*8..+7
  bf16x8 qf[2][2];
#pragma unroll
  for (int qt = 0; qt < 2; ++qt)
#pragma unroll
    for (int ds = 0; ds < 2; ++ds)
      qf[qt][ds] = *(const bf16x8*)&Qh[(wq * 32 + qt * 16 + fr) * 64 + ds * 32 + qd * 8];

  f32x4 zero4 = {0.f, 0.f, 0.f, 0.f};
  f32x4 o_acc[2][4];
  f32x2 l2[2] = {{0.f, 0.f}, {0.f, 0.f}};
#pragma unroll
  for (int mt = 0; mt < 2; ++mt)
#pragma unroll
    for (int dt = 0; dt < 4; ++dt) o_acc[mt][dt] = zero4;

  // ---- prologue: stage K_0 into buf0, full drain ----
#pragma unroll
  for (int p = 0; p < 4; ++p) gload16(kg[p], kl[p]);
#pragma unroll
  for (int p = 0; p < 4; ++p) kg[p] += 128 * 64;  // -> K_1
  __syncthreads();  // vmcnt(0) + barrier: K_0 visible

  int curoff = 0;  // element offset of current K buffer (0 or 8192)
  for (int j = 0; j < 16; ++j) {
    // invariant at top: K_j visible at Ks+curoff; Vts free (prev PV reads done).
    // Issue V_j (oldest 4, waited by vmcnt(4) after softmax) then K_{j+1}
    // prefetch (waited by vmcnt(0) after PV). Last iter's K_17 prefetch reads
    // the next head's K (or start of Vtb for bh=63) -- valid ws, never consumed.
#pragma unroll
    for (int p = 0; p < 4; ++p) gload16(vg[p], vl[p]);
#pragma unroll
    for (int p = 0; p < 4; ++p) gload16(kg[p], kl[p] + (curoff ^ 8192));
#pragma unroll
    for (int p = 0; p < 4; ++p) { kg[p] += 128 * 64; vg[p] += 128; }

    // ---- fused S^T = K·Q^T -> exp2 -> l-sum -> bf16 pack, per key-pair ----
    // st[qt][kt] is final after its kt MFMAs; consume immediately so only the
    // packed bf16 fragments pfw[2][4] (32 regs) stay live, not st[2][8] (64).
    const unsigned short* Kc = Ks + curoff;
    u32x4 pfw[2][4];
#pragma unroll
    for (int ks = 0; ks < 4; ++ks) {
      f32x4 st0[2], st1[2];  // [qt] for kt=2ks, 2ks+1
      st0[0] = zero4; st0[1] = zero4; st1[0] = zero4; st1[1] = zero4;
#pragma unroll
      for (int ds = 0; ds < 2; ++ds) {
        bf16x8 kf0 = *(const bf16x8*)&Kc[kbase[ds] + (2 * ks) * 1024];
        bf16x8 kf1 = *(const bf16x8*)&Kc[kbase[ds] + (2 * ks + 1) * 1024];
        st0[0] = __builtin_amdgcn_mfma_f32_16x16x32_bf16(kf0, qf[0][ds], st0[0], 0, 0, 0);
        st0[1] = __builtin_amdgcn_mfma_f32_16x16x32_bf16(kf0, qf[1][ds], st0[1], 0, 0, 0);
        st1[0] = __builtin_amdgcn_mfma_f32_16x16x32_bf16(kf1, qf[0][ds], st1[0], 0, 0, 0);
        st1[1] = __builtin_amdgcn_mfma_f32_16x16x32_bf16(kf1, qf[1][ds], st1[1], 0, 0, 0);
      }
#pragma unroll
      for (int mt = 0; mt < 2; ++mt) {
#pragma unroll
        for (int r = 0; r < 4; ++r) {
          st0[mt][r] = __builtin_amdgcn_exp2f(st0[mt][r]);
          st1[mt][r] = __builtin_amdgcn_exp2f(st1[mt][r]);
        }
        f32x2 s01 = {st0[mt][0], st0[mt][1]};
        f32x2 s23 = {st0[mt][2], st0[mt][3]};
        f32x2 t01 = {st1[mt][0], st1[mt][1]};
        f32x2 t23 = {st1[mt][2], st1[mt][3]};
        l2[mt] += (s01 + s23) + (t01 + t23);
        u32x4 pk;
        pk[0] = cvtpk(st0[mt][0], st0[mt][1]);
        pk[1] = cvtpk(st0[mt][2], st0[mt][3]);
        pk[2] = cvtpk(st1[mt][0], st1[mt][1]);
        pk[3] = cvtpk(st1[mt][2], st1[mt][3]);
        pfw[mt][ks] = pk;
      }
    }

    // V_j done (oldest 4); K_{j+1} may still be in flight
    asm volatile("s_waitcnt vmcnt(4)" ::: "memory");
    __builtin_amdgcn_s_barrier();

    // ---- O += P · V : A-fragments from packed regs (permuted-key order) ----
#pragma unroll
    for (int ks = 0; ks < 4; ++ks) {
      bf16x8 pf0 = __builtin_bit_cast(bf16x8, pfw[0][ks]);
      bf16x8 pf1 = __builtin_bit_cast(bf16x8, pfw[1][ks]);
#pragma unroll
      for (int dt = 0; dt < 4; ++dt) {
        bf16x8 vf = *(const bf16x8*)&Vts[vbase[ks] + dt * 2048];
        o_acc[0][dt] = __builtin_amdgcn_mfma_f32_16x16x32_bf16(pf0, vf, o_acc[0][dt], 0, 0, 0);
        o_acc[1][dt] = __builtin_amdgcn_mfma_f32_16x16x32_bf16(pf1, vf, o_acc[1][dt], 0, 0, 0);
      }
    }

    // K_{j+1} landed; all waves' Vts reads done -> safe to restage next iter
    asm volatile("s_waitcnt vmcnt(0)" ::: "memory");
    __builtin_amdgcn_s_barrier();
    curoff ^= 8192;
  }

  // reduce l across the 4 lanes sharing each query (fr), once
  float l_red[2];
#pragma unroll
  for (int mt = 0; mt < 2; ++mt) {
    float lv = l2[mt][0] + l2[mt][1];
    lv += __shfl_xor(lv, 16);
    lv += __shfl_xor(lv, 32);
    l_red[mt] = lv;
  }

  // epilogue: normalize, write context [b][s][h*64+d] bf16
  const int b = bh >> 4;
  const int h = bh & 15;
#pragma unroll
  for (int mt = 0; mt < 2; ++mt) {
#pragma unroll
    for (int r = 0; r < 4; ++r) {
      float lv = __shfl(l_red[mt], qd * 4 + r);
      float rl = 1.0f / lv;
      int s = q0 + wq * 32 + mt * 16 + qd * 4 + r;
      size_t base = (((size_t)b * 2048 + s) << 10) + (h << 6);
#pragma unroll
      for (int dt = 0; dt < 4; ++dt) Ctx[base + dt * 16 + fr] = f2bf(o_acc[mt][dt][r] * rl);
    }
  }
}

// ---------------- output projection GEMM (f32 out) ----------------
// r11: XCD-chunked tile swizzle (nwg=512, chunk=64) for A-panel L2 reuse.
__global__ __launch_bounds__(256, 2) void k_gemm_out(
    const unsigned short* __restrict__ Ctx, const unsigned short* __restrict__ Wo,
    const float* __restrict__ bo, float* __restrict__ out) {
  __shared__ unsigned short As[128 * 32];
  __shared__ unsigned short Bs[128 * 32];
  const int tid = threadIdx.x;
  const int lane = tid & 63;
  const int w = tid >> 6;
  const int wm = w & 1;
  const int wn = w >> 1;
  const int lin = blockIdx.x + (blockIdx.y << 3);
  const int swz = ((lin & 7) << 6) + (lin >> 3);
  const int m0 = (swz >> 3) << 7;
  const int n0 = (swz & 7) << 7;

  const int srow = tid >> 2;
  const int sch = (tid & 3) << 3;
  const size_t a0 = (size_t)(m0 + srow) * 1024 + sch;
  const size_t b0 = (size_t)(n0 + srow) * 1024 + sch;

  f32x4 zero4 = {0.f, 0.f, 0.f, 0.f};
  f32x4 acc[4][4];
#pragma unroll
  for (int i = 0; i < 4; ++i)
#pragma unroll
    for (int jj = 0; jj < 4; ++jj) acc[i][jj] = zero4;

  const int fr = lane & 15;
  const int fk = (lane >> 4) << 3;

  for (int kt = 0; kt < 32; ++kt) {
    const int ko = kt << 5;
    __syncthreads();
    gload16(Ctx + a0 + ko, As + tid * 8);
    gload16(Ctx + a0 + (size_t)65536 + ko, As + 2048 + tid * 8);
    gload16(Wo + b0 + ko, Bs + tid * 8);
    gload16(Wo + b0 + (size_t)65536 + ko, Bs + 2048 + tid * 8);
    __syncthreads();
    bf16x8 af[4], bfr[4];
#pragma unroll
    for (int mt = 0; mt < 4; ++mt)
      af[mt] = *(const bf16x8*)&As[(wm * 64 + mt * 16 + fr) * 32 + fk];
#pragma unroll
    for (int nt = 0; nt < 4; ++nt)
      bfr[nt] = *(const bf16x8*)&Bs[(wn * 64 + nt * 16 + fr) * 32 + fk];
#pragma unroll
    for (int mt = 0; mt < 4; ++mt)
#pragma unroll
      for (int nt = 0; nt < 4; ++nt)
        acc[mt][nt] = __builtin_amdgcn_mfma_f32_16x16x32_bf16(af[mt], bfr[nt], acc[mt][nt], 0, 0, 0);
  }

  const int rg = (lane >> 4) << 2;
#pragma unroll
  for (int mt = 0; mt < 4; ++mt) {
    const int mb = m0 + wm * 64 + mt * 16 + rg;
#pragma unroll
    for (int nt = 0; nt < 4; ++nt) {
      const int n = n0 + wn * 64 + nt * 16 + fr;
      const float bvv = bo[n];
#pragma unroll
      for (int r = 0; r < 4; ++r)
        out[(size_t)(mb + r) * 1024 + n] = acc[mt][nt][r] + bvv;
    }
  }
}

// ---------------- host ----------------
extern "C" void kernel_launch(void* const* d_in, const int* in_sizes, int n_in,
                              void* d_out, int out_size, void* d_ws, size_t ws_size,
                              hipStream_t stream) {
  (void)in_sizes; (void)n_in; (void)out_size; (void)ws_size;
  const float* x = (const float*)d_in[0];
  const float* Wq = (const float*)d_in[1];
  const float* bq = (const float*)d_in[2];
  const float* Wk = (const float*)d_in[3];
  const float* bk = (const float*)d_in[4];
  const float* Wv = (const float*)d_in[5];
  const float* bv = (const float*)d_in[6];
  const float* Wo = (const float*)d_in[7];
  const float* bo = (const float*)d_in[8];
  float* out = (float*)d_out;

  unsigned short* xb = (unsigned short*)d_ws;  // 8388608 el
  unsigned short* Wb = xb + 8388608;           // 4194304 el (q,k,v,o)
  unsigned short* Qb = Wb + 4194304;           // [b,h,s,d]
  unsigned short* Kb = Qb + 8388608;           // [b,h,s,d]
  unsigned short* Vtb = Kb + 8388608;          // [b,h,d,s_perm]
  unsigned short* Ctx = xb;                    // reuse xb (dead after k_gemm_qkv)

  k_cvt<<<12288, 256, 0, stream>>>(x, Wq, Wk, Wv, Wo, xb, Wb);
  k_gemm_qkv<<<dim3(8, 64, 3), 256, 0, stream>>>(xb, Wb, bq, bk, bv, Qb, Kb, Vtb);
  k_flash<<<dim3(16, 64), 256, 0, stream>>>(Qb, Kb, Vtb, Ctx);
  k_gemm_out<<<dim3(8, 64), 256, 0, stream>>>(Ctx, Wb + 3 * 1048576, bo, out);
}

// Round 5
// 263.911 us; speedup vs baseline: 1.4337x; 1.0354x over previous
//
#include <hip/hip_runtime.h>

// SelfAttention: B=4, S=2048, D=1024, H=16, Hd=64. f32 in/out, bf16 MFMA inside.

#define LOG2E 1.4426950408889634f
#define QSCALE (0.125f * LOG2E)   // 1/sqrt(64) * log2(e), folded into Wq/bq

typedef __bf16 bf16x8 __attribute__((ext_vector_type(8)));
typedef float f32x4 __attribute__((ext_vector_type(4)));
typedef float f32x2 __attribute__((ext_vector_type(2)));
typedef unsigned short u16x4 __attribute__((ext_vector_type(4)));
typedef unsigned short u16x8 __attribute__((ext_vector_type(8)));
typedef unsigned int u32x4 __attribute__((ext_vector_type(4)));

__device__ __forceinline__ unsigned short f2bf(float f) {
  unsigned int u = __builtin_bit_cast(unsigned int, f);
  u += 0x7fffu + ((u >> 16) & 1u);   // RNE
  return (unsigned short)(u >> 16);
}

// single-instruction pack: bf16(a) low16, bf16(b) high16 (RNE). gfx950 only.
__device__ __forceinline__ unsigned int cvtpk(float a, float b) {
  unsigned int r;
  asm("v_cvt_pk_bf16_f32 %0, %1, %2" : "=v"(r) : "v"(a), "v"(b));
  return r;
}

typedef const __attribute__((address_space(1))) void* gptr_t;
typedef __attribute__((address_space(3))) void* lptr_t;
__device__ __forceinline__ void gload16(const void* g, void* l) {
  __builtin_amdgcn_global_load_lds((gptr_t)g, (lptr_t)l, 16, 0, 0);
}

// ---------------- merged convert kernel ----------------
__global__ __launch_bounds__(256) void k_cvt(const float* __restrict__ x,
                                             const float* __restrict__ Wq, const float* __restrict__ Wk,
                                             const float* __restrict__ Wv, const float* __restrict__ Wo,
                                             unsigned short* __restrict__ xb, unsigned short* __restrict__ Wb) {
  int gi = (blockIdx.x * 256 + threadIdx.x) * 4;
  if (gi < 8388608) {
    f32x4 v = *(const f32x4*)(x + gi);
    u16x4 o; o[0] = f2bf(v[0]); o[1] = f2bf(v[1]); o[2] = f2bf(v[2]); o[3] = f2bf(v[3]);
    *(u16x4*)(xb + gi) = o;
  } else {
    int i = gi - 8388608;
    int wsel = i >> 20;
    int loc = i & 1048575;
    const float* src = (wsel == 0) ? Wq : (wsel == 1) ? Wk : (wsel == 2) ? Wv : Wo;
    float sc = (wsel == 0) ? QSCALE : 1.0f;
    f32x4 v = *(const f32x4*)(src + loc);
    u16x4 o; o[0] = f2bf(v[0] * sc); o[1] = f2bf(v[1] * sc); o[2] = f2bf(v[2] * sc); o[3] = f2bf(v[3] * sc);
    *(u16x4*)(Wb + i) = o;
  }
}

// ---------------- QKV projection GEMM ----------------
// z=0: Q (pre-scaled) -> [b,h,s,d]; z=1: K -> [b,h,s,d];
// z=2: V -> [b,h,d,s_perm] (pos=8q+4h+r for s=16h+4q+r) so flash PV consumes
//      S^T C-layout regs directly as A-operand fragments.
// r11: XCD-chunked tile swizzle (nwg=1536, chunk=192) for A-panel L2 reuse.
__global__ __launch_bounds__(256, 2) void k_gemm_qkv(
    const unsigned short* __restrict__ xb, const unsigned short* __restrict__ Wb,
    const float* __restrict__ bq, const float* __restrict__ bk, const float* __restrict__ bv,
    unsigned short* __restrict__ Qb, unsigned short* __restrict__ Kb, unsigned short* __restrict__ Vtb) {
  __shared__ unsigned short As[128 * 32];
  __shared__ unsigned short Bs[128 * 32];
  const int tid = threadIdx.x;
  const int lane = tid & 63;
  const int w = tid >> 6;
  const int wm = w & 1;
  const int wn = w >> 1;
  const int lin = blockIdx.x + (blockIdx.y << 3) + (blockIdx.z << 9);
  const int swz = (lin & 7) * 192 + (lin >> 3);
  const int z = swz >> 9;
  const int m0 = ((swz >> 3) & 63) << 7;
  const int n0 = (swz & 7) << 7;
  const unsigned short* W = Wb + ((size_t)z << 20);

  const int srow = tid >> 2;
  const int sch = (tid & 3) << 3;
  const size_t a0 = (size_t)(m0 + srow) * 1024 + sch;
  const size_t b0 = (size_t)(n0 + srow) * 1024 + sch;

  f32x4 zero4 = {0.f, 0.f, 0.f, 0.f};
  f32x4 acc[4][4];
#pragma unroll
  for (int i = 0; i < 4; ++i)
#pragma unroll
    for (int jj = 0; jj < 4; ++jj) acc[i][jj] = zero4;

  const int fr = lane & 15;
  const int fk = (lane >> 4) << 3;

  for (int kt = 0; kt < 32; ++kt) {
    const int ko = kt << 5;
    __syncthreads();
    gload16(xb + a0 + ko, As + tid * 8);
    gload16(xb + a0 + (size_t)65536 + ko, As + 2048 + tid * 8);
    gload16(W + b0 + ko, Bs + tid * 8);
    gload16(W + b0 + (size_t)65536 + ko, Bs + 2048 + tid * 8);
    __syncthreads();
    bf16x8 af[4], bfr[4];
#pragma unroll
    for (int mt = 0; mt < 4; ++mt)
      af[mt] = *(const bf16x8*)&As[(wm * 64 + mt * 16 + fr) * 32 + fk];
#pragma unroll
    for (int nt = 0; nt < 4; ++nt)
      bfr[nt] = *(const bf16x8*)&Bs[(wn * 64 + nt * 16 + fr) * 32 + fk];
#pragma unroll
    for (int mt = 0; mt < 4; ++mt)
#pragma unroll
      for (int nt = 0; nt < 4; ++nt)
        acc[mt][nt] = __builtin_amdgcn_mfma_f32_16x16x32_bf16(af[mt], bfr[nt], acc[mt][nt], 0, 0, 0);
  }

  const float* bias = (z == 0) ? bq : (z == 1) ? bk : bv;
  const float bsc = (z == 0) ? QSCALE : 1.0f;
  const int rg = (lane >> 4) << 2;
#pragma unroll
  for (int mt = 0; mt < 4; ++mt) {
    const int mb = m0 + wm * 64 + mt * 16 + rg;
    const int b = mb >> 11;
    const int s = mb & 2047;
#pragma unroll
    for (int nt = 0; nt < 4; ++nt) {
      const int n = n0 + wn * 64 + nt * 16 + fr;
      const float bvv = bias[n] * bsc;
      const int h = n >> 6;
      const int d = n & 63;
      if (z == 2) {
        u16x4 pk;
#pragma unroll
        for (int r = 0; r < 4; ++r) pk[r] = f2bf(acc[mt][nt][r] + bvv);
        const int pbase = (s & ~31) | ((s & 12) << 1) | ((s & 16) >> 2);
        *(u16x4*)&Vtb[(((size_t)(b * 16 + h) << 6) + d) * 2048 + pbase] = pk;
      } else {
        unsigned short* O = (z == 0) ? Qb : Kb;
#pragma unroll
        for (int r = 0; r < 4; ++r)
          O[(((size_t)(b * 16 + h) << 11) + s + r) * 64 + d] = f2bf(acc[mt][nt][r] + bvv);
      }
    }
  }
}

// ---------------- flash attention (S^T, no-max softmax, register P) ----------
// r12: QBLK 128->256, 8 waves (512 threads), same 48KB LDS and same per-wave
// work (32q). Rationale: r11 showed Occupancy 24%, both pipes <45% -> stall-
// bound on TLP; LDS capped 3 blocks/CU and the 1024-block grid had a 4-round
// tail. Now: 512 blocks = exactly 2/CU, one round, 16 waves/CU; staged K/V
// bytes per MFMA halve (8 waves share each stage). launch_bounds(512,4) ->
// 128-reg cap (unified use ~104, headroom ~24 -- WRITE_SIZE is the spill
// tripwire). vmcnt counts: 2 V-loads + 2 K-loads per thread -> vmcnt(2) V-wait.
// Plus T5 setprio(1) around MFMA clusters. Pipeline schedule itself unchanged.
__global__ __launch_bounds__(512, 4) void k_flash(
    const unsigned short* __restrict__ Qb, const unsigned short* __restrict__ Kb,
    const unsigned short* __restrict__ Vtb, unsigned short* __restrict__ Ctx) {
  __shared__ unsigned short Ks[2 * 128 * 64];  // 32KB double-buffered [key][64d], 3-bit chunk xor
  __shared__ unsigned short Vts[64 * 128];     // 16KB [d][128k_perm], 4-bit chunk xor
  const int tid = threadIdx.x;
  const int lane = tid & 63;
  const int wq = tid >> 6;           // 0..7
  const int fr = lane & 15;
  const int qd = lane >> 4;
  const int lin = blockIdx.x + (blockIdx.y << 3);        // 0..511
  const int swz = ((lin & 7) << 6) + (lin >> 3);         // chunk 64 per XCD
  const int bh = swz >> 3;                               // 0..63
  const int q0 = (swz & 7) << 8;                         // 0..1792
  const size_t hoff = (size_t)bh << 17;  // 2048*64
  const unsigned short* Qh = Qb + hoff + ((size_t)q0 << 6);

  // ---- hoisted staging addresses (advance by constant stride per j) ----
  const unsigned short* kg[2];
  const unsigned short* vg[2];
  unsigned short* kl[2];
  unsigned short* vl[2];
#pragma unroll
  for (int p = 0; p < 2; ++p) {
    int slot = p * 512 + tid;
    int kr = slot >> 3, ch = slot & 7;
    kg[p] = Kb + hoff + (size_t)kr * 64 + ((ch ^ (kr & 7)) << 3);
    kl[p] = Ks + slot * 8;
    int dr = slot >> 4, ch2 = slot & 15;
    vg[p] = Vtb + hoff + (size_t)dr * 2048 + ((ch2 ^ (dr & 15)) << 3);
    vl[p] = Vts + slot * 8;
  }

  // ---- slim LDS read base offsets (kt/dt terms fold to ds_read immediates) ----
  int kbase[2];
#pragma unroll
  for (int ds = 0; ds < 2; ++ds)
    kbase[ds] = fr * 64 + (((ds * 4 + qd) ^ (fr & 7)) << 3);
  int vbase[4];
#pragma unroll
  for (int ks = 0; ks < 4; ++ks)
    vbase[ks] = fr * 128 + (((ks * 4 + qd) ^ fr) << 3);

  // Q fragments: B[n=query][k=d]; row = wq*32+qt*16+fr, d = ds*32+qd*8..+7
  bf16x8 qf[2][2];
#pragma unroll
  for (int qt = 0; qt < 2; ++qt)
#pragma unroll
    for (int ds = 0; ds < 2; ++ds)
      qf[qt][ds] = *(const bf16x8*)&Qh[(wq * 32 + qt * 16 + fr) * 64 + ds * 32 + qd * 8];

  f32x4 zero4 = {0.f, 0.f, 0.f, 0.f};
  f32x4 o_acc[2][4];
  f32x2 l2[2] = {{0.f, 0.f}, {0.f, 0.f}};
#pragma unroll
  for (int mt = 0; mt < 2; ++mt)
#pragma unroll
    for (int dt = 0; dt < 4; ++dt) o_acc[mt][dt] = zero4;

  // ---- prologue: stage K_0 into buf0, full drain ----
#pragma unroll
  for (int p = 0; p < 2; ++p) gload16(kg[p], kl[p]);
#pragma unroll
  for (int p = 0; p < 2; ++p) kg[p] += 128 * 64;  // -> K_1
  __syncthreads();  // vmcnt(0) + barrier: K_0 visible

  int curoff = 0;  // element offset of current K buffer (0 or 8192)
  for (int j = 0; j < 16; ++j) {
    // invariant at top: K_j visible at Ks+curoff; Vts free (prev PV reads done).
    // Issue V_j (oldest 2, waited by vmcnt(2) after softmax) then K_{j+1}
    // prefetch (waited by vmcnt(0) after PV). Last iter's K_17 prefetch reads
    // past Kb into Vtb -- valid workspace, never consumed.
#pragma unroll
    for (int p = 0; p < 2; ++p) gload16(vg[p], vl[p]);
#pragma unroll
    for (int p = 0; p < 2; ++p) gload16(kg[p], kl[p] + (curoff ^ 8192));
#pragma unroll
    for (int p = 0; p < 2; ++p) { kg[p] += 128 * 64; vg[p] += 128; }

    // ---- fused S^T = K·Q^T -> exp2 -> l-sum -> bf16 pack, per key-pair ----
    const unsigned short* Kc = Ks + curoff;
    u32x4 pfw[2][4];
#pragma unroll
    for (int ks = 0; ks < 4; ++ks) {
      f32x4 st0[2], st1[2];  // [qt] for kt=2ks, 2ks+1
      st0[0] = zero4; st0[1] = zero4; st1[0] = zero4; st1[1] = zero4;
      __builtin_amdgcn_s_setprio(1);
#pragma unroll
      for (int ds = 0; ds < 2; ++ds) {
        bf16x8 kf0 = *(const bf16x8*)&Kc[kbase[ds] + (2 * ks) * 1024];
        bf16x8 kf1 = *(const bf16x8*)&Kc[kbase[ds] + (2 * ks + 1) * 1024];
        st0[0] = __builtin_amdgcn_mfma_f32_16x16x32_bf16(kf0, qf[0][ds], st0[0], 0, 0, 0);
        st0[1] = __builtin_amdgcn_mfma_f32_16x16x32_bf16(kf0, qf[1][ds], st0[1], 0, 0, 0);
        st1[0] = __builtin_amdgcn_mfma_f32_16x16x32_bf16(kf1, qf[0][ds], st1[0], 0, 0, 0);
        st1[1] = __builtin_amdgcn_mfma_f32_16x16x32_bf16(kf1, qf[1][ds], st1[1], 0, 0, 0);
      }
      __builtin_amdgcn_s_setprio(0);
#pragma unroll
      for (int mt = 0; mt < 2; ++mt) {
#pragma unroll
        for (int r = 0; r < 4; ++r) {
          st0[mt][r] = __builtin_amdgcn_exp2f(st0[mt][r]);
          st1[mt][r] = __builtin_amdgcn_exp2f(st1[mt][r]);
        }
        f32x2 s01 = {st0[mt][0], st0[mt][1]};
        f32x2 s23 = {st0[mt][2], st0[mt][3]};
        f32x2 t01 = {st1[mt][0], st1[mt][1]};
        f32x2 t23 = {st1[mt][2], st1[mt][3]};
        l2[mt] += (s01 + s23) + (t01 + t23);
        u32x4 pk;
        pk[0] = cvtpk(st0[mt][0], st0[mt][1]);
        pk[1] = cvtpk(st0[mt][2], st0[mt][3]);
        pk[2] = cvtpk(st1[mt][0], st1[mt][1]);
        pk[3] = cvtpk(st1[mt][2], st1[mt][3]);
        pfw[mt][ks] = pk;
      }
    }

    // V_j done (oldest 2); K_{j+1} may still be in flight
    asm volatile("s_waitcnt vmcnt(2)" ::: "memory");
    __builtin_amdgcn_s_barrier();

    // ---- O += P · V : A-fragments from packed regs (permuted-key order) ----
    __builtin_amdgcn_s_setprio(1);
#pragma unroll
    for (int ks = 0; ks < 4; ++ks) {
      bf16x8 pf0 = __builtin_bit_cast(bf16x8, pfw[0][ks]);
      bf16x8 pf1 = __builtin_bit_cast(bf16x8, pfw[1][ks]);
#pragma unroll
      for (int dt = 0; dt < 4; ++dt) {
        bf16x8 vf = *(const bf16x8*)&Vts[vbase[ks] + dt * 2048];
        o_acc[0][dt] = __builtin_amdgcn_mfma_f32_16x16x32_bf16(pf0, vf, o_acc[0][dt], 0, 0, 0);
        o_acc[1][dt] = __builtin_amdgcn_mfma_f32_16x16x32_bf16(pf1, vf, o_acc[1][dt], 0, 0, 0);
      }
    }
    __builtin_amdgcn_s_setprio(0);

    // K_{j+1} landed; all waves' Vts reads done -> safe to restage next iter
    asm volatile("s_waitcnt vmcnt(0)" ::: "memory");
    __builtin_amdgcn_s_barrier();
    curoff ^= 8192;
  }

  // reduce l across the 4 lanes sharing each query (fr), once
  float l_red[2];
#pragma unroll
  for (int mt = 0; mt < 2; ++mt) {
    float lv = l2[mt][0] + l2[mt][1];
    lv += __shfl_xor(lv, 16);
    lv += __shfl_xor(lv, 32);
    l_red[mt] = lv;
  }

  // epilogue: normalize, write context [b][s][h*64+d] bf16
  const int b = bh >> 4;
  const int h = bh & 15;
#pragma unroll
  for (int mt = 0; mt < 2; ++mt) {
#pragma unroll
    for (int r = 0; r < 4; ++r) {
      float lv = __shfl(l_red[mt], qd * 4 + r);
      float rl = 1.0f / lv;
      int s = q0 + wq * 32 + mt * 16 + qd * 4 + r;
      size_t base = (((size_t)b * 2048 + s) << 10) + (h << 6);
#pragma unroll
      for (int dt = 0; dt < 4; ++dt) Ctx[base + dt * 16 + fr] = f2bf(o_acc[mt][dt][r] * rl);
    }
  }
}

// ---------------- output projection GEMM (f32 out) ----------------
// r11: XCD-chunked tile swizzle (nwg=512, chunk=64) for A-panel L2 reuse.
__global__ __launch_bounds__(256, 2) void k_gemm_out(
    const unsigned short* __restrict__ Ctx, const unsigned short* __restrict__ Wo,
    const float* __restrict__ bo, float* __restrict__ out) {
  __shared__ unsigned short As[128 * 32];
  __shared__ unsigned short Bs[128 * 32];
  const int tid = threadIdx.x;
  const int lane = tid & 63;
  const int w = tid >> 6;
  const int wm = w & 1;
  const int wn = w >> 1;
  const int lin = blockIdx.x + (blockIdx.y << 3);
  const int swz = ((lin & 7) << 6) + (lin >> 3);
  const int m0 = (swz >> 3) << 7;
  const int n0 = (swz & 7) << 7;

  const int srow = tid >> 2;
  const int sch = (tid & 3) << 3;
  const size_t a0 = (size_t)(m0 + srow) * 1024 + sch;
  const size_t b0 = (size_t)(n0 + srow) * 1024 + sch;

  f32x4 zero4 = {0.f, 0.f, 0.f, 0.f};
  f32x4 acc[4][4];
#pragma unroll
  for (int i = 0; i < 4; ++i)
#pragma unroll
    for (int jj = 0; jj < 4; ++jj) acc[i][jj] = zero4;

  const int fr = lane & 15;
  const int fk = (lane >> 4) << 3;

  for (int kt = 0; kt < 32; ++kt) {
    const int ko = kt << 5;
    __syncthreads();
    gload16(Ctx + a0 + ko, As + tid * 8);
    gload16(Ctx + a0 + (size_t)65536 + ko, As + 2048 + tid * 8);
    gload16(Wo + b0 + ko, Bs + tid * 8);
    gload16(Wo + b0 + (size_t)65536 + ko, Bs + 2048 + tid * 8);
    __syncthreads();
    bf16x8 af[4], bfr[4];
#pragma unroll
    for (int mt = 0; mt < 4; ++mt)
      af[mt] = *(const bf16x8*)&As[(wm * 64 + mt * 16 + fr) * 32 + fk];
#pragma unroll
    for (int nt = 0; nt < 4; ++nt)
      bfr[nt] = *(const bf16x8*)&Bs[(wn * 64 + nt * 16 + fr) * 32 + fk];
#pragma unroll
    for (int mt = 0; mt < 4; ++mt)
#pragma unroll
      for (int nt = 0; nt < 4; ++nt)
        acc[mt][nt] = __builtin_amdgcn_mfma_f32_16x16x32_bf16(af[mt], bfr[nt], acc[mt][nt], 0, 0, 0);
  }

  const int rg = (lane >> 4) << 2;
#pragma unroll
  for (int mt = 0; mt < 4; ++mt) {
    const int mb = m0 + wm * 64 + mt * 16 + rg;
#pragma unroll
    for (int nt = 0; nt < 4; ++nt) {
      const int n = n0 + wn * 64 + nt * 16 + fr;
      const float bvv = bo[n];
#pragma unroll
      for (int r = 0; r < 4; ++r)
        out[(size_t)(mb + r) * 1024 + n] = acc[mt][nt][r] + bvv;
    }
  }
}

// ---------------- host ----------------
extern "C" void kernel_launch(void* const* d_in, const int* in_sizes, int n_in,
                              void* d_out, int out_size, void* d_ws, size_t ws_size,
                              hipStream_t stream) {
  (void)in_sizes; (void)n_in; (void)out_size; (void)ws_size;
  const float* x = (const float*)d_in[0];
  const float* Wq = (const float*)d_in[1];
  const float* bq = (const float*)d_in[2];
  const float* Wk = (const float*)d_in[3];
  const float* bk = (const float*)d_in[4];
  const float* Wv = (const float*)d_in[5];
  const float* bv = (const float*)d_in[6];
  const float* Wo = (const float*)d_in[7];
  const float* bo = (const float*)d_in[8];
  float* out = (float*)d_out;

  unsigned short* xb = (unsigned short*)d_ws;  // 8388608 el
  unsigned short* Wb = xb + 8388608;           // 4194304 el (q,k,v,o)
  unsigned short* Qb = Wb + 4194304;           // [b,h,s,d]
  unsigned short* Kb = Qb + 8388608;           // [b,h,s,d]
  unsigned short* Vtb = Kb + 8388608;          // [b,h,d,s_perm]
  unsigned short* Ctx = xb;                    // reuse xb (dead after k_gemm_qkv)

  k_cvt<<<12288, 256, 0, stream>>>(x, Wq, Wk, Wv, Wo, xb, Wb);
  k_gemm_qkv<<<dim3(8, 64, 3), 256, 0, stream>>>(xb, Wb, bq, bk, bv, Qb, Kb, Vtb);
  k_flash<<<dim3(8, 64), 512, 0, stream>>>(Qb, Kb, Vtb, Ctx);
  k_gemm_out<<<dim3(8, 64), 256, 0, stream>>>(Ctx, Wb + 3 * 1048576, bo, out);
}

// Round 6
// 263.014 us; speedup vs baseline: 1.4386x; 1.0034x over previous
//
#include <hip/hip_runtime.h>

// SelfAttention: B=4, S=2048, D=1024, H=16, Hd=64. f32 in/out, bf16 MFMA inside.

#define LOG2E 1.4426950408889634f
#define QSCALE (0.125f * LOG2E)   // 1/sqrt(64) * log2(e), folded into Wq/bq

typedef __bf16 bf16x8 __attribute__((ext_vector_type(8)));
typedef float f32x4 __attribute__((ext_vector_type(4)));
typedef float f32x2 __attribute__((ext_vector_type(2)));
typedef unsigned short u16x4 __attribute__((ext_vector_type(4)));
typedef unsigned short u16x8 __attribute__((ext_vector_type(8)));
typedef unsigned int u32x4 __attribute__((ext_vector_type(4)));

__device__ __forceinline__ unsigned short f2bf(float f) {
  unsigned int u = __builtin_bit_cast(unsigned int, f);
  u += 0x7fffu + ((u >> 16) & 1u);   // RNE
  return (unsigned short)(u >> 16);
}

// single-instruction pack: bf16(a) low16, bf16(b) high16 (RNE). gfx950 only.
__device__ __forceinline__ unsigned int cvtpk(float a, float b) {
  unsigned int r;
  asm("v_cvt_pk_bf16_f32 %0, %1, %2" : "=v"(r) : "v"(a), "v"(b));
  return r;
}

typedef const __attribute__((address_space(1))) void* gptr_t;
typedef __attribute__((address_space(3))) void* lptr_t;
__device__ __forceinline__ void gload16(const void* g, void* l) {
  __builtin_amdgcn_global_load_lds((gptr_t)g, (lptr_t)l, 16, 0, 0);
}

// ---------------- merged convert kernel ----------------
__global__ __launch_bounds__(256) void k_cvt(const float* __restrict__ x,
                                             const float* __restrict__ Wq, const float* __restrict__ Wk,
                                             const float* __restrict__ Wv, const float* __restrict__ Wo,
                                             unsigned short* __restrict__ xb, unsigned short* __restrict__ Wb) {
  int gi = (blockIdx.x * 256 + threadIdx.x) * 4;
  if (gi < 8388608) {
    f32x4 v = *(const f32x4*)(x + gi);
    u16x4 o; o[0] = f2bf(v[0]); o[1] = f2bf(v[1]); o[2] = f2bf(v[2]); o[3] = f2bf(v[3]);
    *(u16x4*)(xb + gi) = o;
  } else {
    int i = gi - 8388608;
    int wsel = i >> 20;
    int loc = i & 1048575;
    const float* src = (wsel == 0) ? Wq : (wsel == 1) ? Wk : (wsel == 2) ? Wv : Wo;
    float sc = (wsel == 0) ? QSCALE : 1.0f;
    f32x4 v = *(const f32x4*)(src + loc);
    u16x4 o; o[0] = f2bf(v[0] * sc); o[1] = f2bf(v[1] * sc); o[2] = f2bf(v[2] * sc); o[3] = f2bf(v[3] * sc);
    *(u16x4*)(Wb + i) = o;
  }
}

// ---------------- QKV projection GEMM ----------------
// z=0: Q (pre-scaled) -> [b,h,s,d]; z=1: K -> [b,h,s,d];
// z=2: V -> [b,h,d,s_perm] so flash PV consumes S^T C-layout regs directly.
// r13: (1) double-buffered LDS K-pipeline (stage kt+1 before compute kt;
// vmcnt(4)+bar; ds_read; lgkmcnt(0)+bar; MFMA) -- stage latency spans a full
// K-step instead of a vmcnt(0) drain per iter. (2) paired-row XOR LDS swizzle:
// two 64B logical rows per 128B LDS row, slot s = c ^ (R&7); pre-swizzled
// GLOBAL source (gload_lds dest linear) + same XOR on read -> 0 bank conflicts
// (was 6.29M conflict-cycles). (3) launch_bounds(256,3): ~130 unified regs.
__global__ __launch_bounds__(256, 3) void k_gemm_qkv(
    const unsigned short* __restrict__ xb, const unsigned short* __restrict__ Wb,
    const float* __restrict__ bq, const float* __restrict__ bk, const float* __restrict__ bv,
    unsigned short* __restrict__ Qb, unsigned short* __restrict__ Kb, unsigned short* __restrict__ Vtb) {
  __shared__ unsigned short As[2 * 4096];  // 16KB: 2 bufs x 64 rows x 128B (paired-row swz)
  __shared__ unsigned short Bs[2 * 4096];
  const int tid = threadIdx.x;
  const int lane = tid & 63;
  const int w = tid >> 6;
  const int wm = w & 1;
  const int wn = w >> 1;
  const int lin = blockIdx.x + (blockIdx.y << 3) + (blockIdx.z << 9);
  const int swz = (lin & 7) * 192 + (lin >> 3);
  const int z = swz >> 9;
  const int m0 = ((swz >> 3) & 63) << 7;
  const int n0 = (swz & 7) << 7;
  const unsigned short* W = Wb + ((size_t)z << 20);

  // ---- pre-swizzled staging source: thread tid owns LDS 16B slot tid ----
  // R = tid>>3, s = tid&7; logical chunk c = s ^ (R&7); mrow = 2R + (c>>2),
  // kchunk = c&3. p=1 adds +64 rows (same c since 32 = 0 mod 8).
  const int sR = tid >> 3;
  const int sc_ = (tid & 7) ^ (sR & 7);
  const int mrow0 = 2 * sR + (sc_ >> 2);
  const int kc0 = (sc_ & 3) << 3;
  const unsigned short* srcA = xb + (size_t)(m0 + mrow0) * 1024 + kc0;
  const unsigned short* srcB = W + (size_t)(n0 + mrow0) * 1024 + kc0;
  unsigned short* dstA = As + tid * 8;
  unsigned short* dstB = Bs + tid * 8;

  // ---- swizzled LDS read offsets (shorts; kt-invariant) ----
  const int fr = lane & 15;
  const int kq = lane >> 4;  // k-chunk 0..3
  int aoff[4], boff[4];
#pragma unroll
  for (int t = 0; t < 4; ++t) {
    int ra = wm * 64 + t * 16 + fr;
    aoff[t] = ((ra >> 1) << 6) + (((((ra & 1) << 2) + kq) ^ ((ra >> 1) & 7)) << 3);
    int rb = wn * 64 + t * 16 + fr;
    boff[t] = ((rb >> 1) << 6) + (((((rb & 1) << 2) + kq) ^ ((rb >> 1) & 7)) << 3);
  }

  f32x4 zero4 = {0.f, 0.f, 0.f, 0.f};
  f32x4 acc[4][4];
#pragma unroll
  for (int i = 0; i < 4; ++i)
#pragma unroll
    for (int jj = 0; jj < 4; ++jj) acc[i][jj] = zero4;

  // ---- prologue: stage kt=0 into buf0 ----
  gload16(srcA, dstA);
  gload16(srcA + 65536, dstA + 2048);
  gload16(srcB, dstB);
  gload16(srcB + 65536, dstB + 2048);

  int cur = 0;
  for (int kt = 0; kt < 32; ++kt) {
    // stage kt+1 (wrapped; last iter harmlessly re-stages kt=0) into buf^1
    const int kon = ((kt + 1) & 31) << 5;
    const int soff = (cur ^ 1) << 12;
    gload16(srcA + kon, dstA + soff);
    gload16(srcA + 65536 + kon, dstA + soff + 2048);
    gload16(srcB + kon, dstB + soff);
    gload16(srcB + 65536 + kon, dstB + soff + 2048);

    // buf[cur] (kt) visible; kt+1's 4 loads stay in flight
    asm volatile("s_waitcnt vmcnt(4)" ::: "memory");
    __builtin_amdgcn_s_barrier();

    const unsigned short* Ac = As + (cur << 12);
    const unsigned short* Bc = Bs + (cur << 12);
    bf16x8 af[4], bfr[4];
#pragma unroll
    for (int mt = 0; mt < 4; ++mt) af[mt] = *(const bf16x8*)&Ac[aoff[mt]];
#pragma unroll
    for (int nt = 0; nt < 4; ++nt) bfr[nt] = *(const bf16x8*)&Bc[boff[nt]];

    // all reads landed -> next iter may overwrite buf[cur]
    asm volatile("s_waitcnt lgkmcnt(0)" ::: "memory");
    __builtin_amdgcn_s_barrier();

    __builtin_amdgcn_s_setprio(1);
#pragma unroll
    for (int mt = 0; mt < 4; ++mt)
#pragma unroll
      for (int nt = 0; nt < 4; ++nt)
        acc[mt][nt] = __builtin_amdgcn_mfma_f32_16x16x32_bf16(af[mt], bfr[nt], acc[mt][nt], 0, 0, 0);
    __builtin_amdgcn_s_setprio(0);
    cur ^= 1;
  }

  const float* bias = (z == 0) ? bq : (z == 1) ? bk : bv;
  const float bsc = (z == 0) ? QSCALE : 1.0f;
  const int rg = kq << 2;
#pragma unroll
  for (int mt = 0; mt < 4; ++mt) {
    const int mb = m0 + wm * 64 + mt * 16 + rg;
    const int b = mb >> 11;
    const int s = mb & 2047;
#pragma unroll
    for (int nt = 0; nt < 4; ++nt) {
      const int n = n0 + wn * 64 + nt * 16 + fr;
      const float bvv = bias[n] * bsc;
      const int h = n >> 6;
      const int d = n & 63;
      if (z == 2) {
        u16x4 pk;
#pragma unroll
        for (int r = 0; r < 4; ++r) pk[r] = f2bf(acc[mt][nt][r] + bvv);
        const int pbase = (s & ~31) | ((s & 12) << 1) | ((s & 16) >> 2);
        *(u16x4*)&Vtb[(((size_t)(b * 16 + h) << 6) + d) * 2048 + pbase] = pk;
      } else {
        unsigned short* O = (z == 0) ? Qb : Kb;
#pragma unroll
        for (int r = 0; r < 4; ++r)
          O[(((size_t)(b * 16 + h) << 11) + s + r) * 64 + d] = f2bf(acc[mt][nt][r] + bvv);
      }
    }
  }
}

// ---------------- flash attention (S^T, no-max softmax, register P) ----------
// r12 (unchanged in r13): 8 waves/512 thr, QBLK=256, 48KB LDS, 2 blocks/CU;
// V_j hidden under QK^T via vmcnt(2); K_{j+1} dbuf via vmcnt(0) at iter end;
// setprio around MFMA clusters.
__global__ __launch_bounds__(512, 4) void k_flash(
    const unsigned short* __restrict__ Qb, const unsigned short* __restrict__ Kb,
    const unsigned short* __restrict__ Vtb, unsigned short* __restrict__ Ctx) {
  __shared__ unsigned short Ks[2 * 128 * 64];  // 32KB double-buffered [key][64d], 3-bit chunk xor
  __shared__ unsigned short Vts[64 * 128];     // 16KB [d][128k_perm], 4-bit chunk xor
  const int tid = threadIdx.x;
  const int lane = tid & 63;
  const int wq = tid >> 6;           // 0..7
  const int fr = lane & 15;
  const int qd = lane >> 4;
  const int lin = blockIdx.x + (blockIdx.y << 3);        // 0..511
  const int swz = ((lin & 7) << 6) + (lin >> 3);         // chunk 64 per XCD
  const int bh = swz >> 3;                               // 0..63
  const int q0 = (swz & 7) << 8;                         // 0..1792
  const size_t hoff = (size_t)bh << 17;  // 2048*64
  const unsigned short* Qh = Qb + hoff + ((size_t)q0 << 6);

  // ---- hoisted staging addresses (advance by constant stride per j) ----
  const unsigned short* kg[2];
  const unsigned short* vg[2];
  unsigned short* kl[2];
  unsigned short* vl[2];
#pragma unroll
  for (int p = 0; p < 2; ++p) {
    int slot = p * 512 + tid;
    int kr = slot >> 3, ch = slot & 7;
    kg[p] = Kb + hoff + (size_t)kr * 64 + ((ch ^ (kr & 7)) << 3);
    kl[p] = Ks + slot * 8;
    int dr = slot >> 4, ch2 = slot & 15;
    vg[p] = Vtb + hoff + (size_t)dr * 2048 + ((ch2 ^ (dr & 15)) << 3);
    vl[p] = Vts + slot * 8;
  }

  // ---- slim LDS read base offsets (kt/dt terms fold to ds_read immediates) ----
  int kbase[2];
#pragma unroll
  for (int ds = 0; ds < 2; ++ds)
    kbase[ds] = fr * 64 + (((ds * 4 + qd) ^ (fr & 7)) << 3);
  int vbase[4];
#pragma unroll
  for (int ks = 0; ks < 4; ++ks)
    vbase[ks] = fr * 128 + (((ks * 4 + qd) ^ fr) << 3);

  // Q fragments: B[n=query][k=d]; row = wq*32+qt*16+fr, d = ds*32+qd*8..+7
  bf16x8 qf[2][2];
#pragma unroll
  for (int qt = 0; qt < 2; ++qt)
#pragma unroll
    for (int ds = 0; ds < 2; ++ds)
      qf[qt][ds] = *(const bf16x8*)&Qh[(wq * 32 + qt * 16 + fr) * 64 + ds * 32 + qd * 8];

  f32x4 zero4 = {0.f, 0.f, 0.f, 0.f};
  f32x4 o_acc[2][4];
  f32x2 l2[2] = {{0.f, 0.f}, {0.f, 0.f}};
#pragma unroll
  for (int mt = 0; mt < 2; ++mt)
#pragma unroll
    for (int dt = 0; dt < 4; ++dt) o_acc[mt][dt] = zero4;

  // ---- prologue: stage K_0 into buf0, full drain ----
#pragma unroll
  for (int p = 0; p < 2; ++p) gload16(kg[p], kl[p]);
#pragma unroll
  for (int p = 0; p < 2; ++p) kg[p] += 128 * 64;  // -> K_1
  __syncthreads();  // vmcnt(0) + barrier: K_0 visible

  int curoff = 0;  // element offset of current K buffer (0 or 8192)
  for (int j = 0; j < 16; ++j) {
#pragma unroll
    for (int p = 0; p < 2; ++p) gload16(vg[p], vl[p]);
#pragma unroll
    for (int p = 0; p < 2; ++p) gload16(kg[p], kl[p] + (curoff ^ 8192));
#pragma unroll
    for (int p = 0; p < 2; ++p) { kg[p] += 128 * 64; vg[p] += 128; }

    // ---- fused S^T = K·Q^T -> exp2 -> l-sum -> bf16 pack, per key-pair ----
    const unsigned short* Kc = Ks + curoff;
    u32x4 pfw[2][4];
#pragma unroll
    for (int ks = 0; ks < 4; ++ks) {
      f32x4 st0[2], st1[2];  // [qt] for kt=2ks, 2ks+1
      st0[0] = zero4; st0[1] = zero4; st1[0] = zero4; st1[1] = zero4;
      __builtin_amdgcn_s_setprio(1);
#pragma unroll
      for (int ds = 0; ds < 2; ++ds) {
        bf16x8 kf0 = *(const bf16x8*)&Kc[kbase[ds] + (2 * ks) * 1024];
        bf16x8 kf1 = *(const bf16x8*)&Kc[kbase[ds] + (2 * ks + 1) * 1024];
        st0[0] = __builtin_amdgcn_mfma_f32_16x16x32_bf16(kf0, qf[0][ds], st0[0], 0, 0, 0);
        st0[1] = __builtin_amdgcn_mfma_f32_16x16x32_bf16(kf0, qf[1][ds], st0[1], 0, 0, 0);
        st1[0] = __builtin_amdgcn_mfma_f32_16x16x32_bf16(kf1, qf[0][ds], st1[0], 0, 0, 0);
        st1[1] = __builtin_amdgcn_mfma_f32_16x16x32_bf16(kf1, qf[1][ds], st1[1], 0, 0, 0);
      }
      __builtin_amdgcn_s_setprio(0);
#pragma unroll
      for (int mt = 0; mt < 2; ++mt) {
#pragma unroll
        for (int r = 0; r < 4; ++r) {
          st0[mt][r] = __builtin_amdgcn_exp2f(st0[mt][r]);
          st1[mt][r] = __builtin_amdgcn_exp2f(st1[mt][r]);
        }
        f32x2 s01 = {st0[mt][0], st0[mt][1]};
        f32x2 s23 = {st0[mt][2], st0[mt][3]};
        f32x2 t01 = {st1[mt][0], st1[mt][1]};
        f32x2 t23 = {st1[mt][2], st1[mt][3]};
        l2[mt] += (s01 + s23) + (t01 + t23);
        u32x4 pk;
        pk[0] = cvtpk(st0[mt][0], st0[mt][1]);
        pk[1] = cvtpk(st0[mt][2], st0[mt][3]);
        pk[2] = cvtpk(st1[mt][0], st1[mt][1]);
        pk[3] = cvtpk(st1[mt][2], st1[mt][3]);
        pfw[mt][ks] = pk;
      }
    }

    // V_j done (oldest 2); K_{j+1} may still be in flight
    asm volatile("s_waitcnt vmcnt(2)" ::: "memory");
    __builtin_amdgcn_s_barrier();

    // ---- O += P · V : A-fragments from packed regs (permuted-key order) ----
    __builtin_amdgcn_s_setprio(1);
#pragma unroll
    for (int ks = 0; ks < 4; ++ks) {
      bf16x8 pf0 = __builtin_bit_cast(bf16x8, pfw[0][ks]);
      bf16x8 pf1 = __builtin_bit_cast(bf16x8, pfw[1][ks]);
#pragma unroll
      for (int dt = 0; dt < 4; ++dt) {
        bf16x8 vf = *(const bf16x8*)&Vts[vbase[ks] + dt * 2048];
        o_acc[0][dt] = __builtin_amdgcn_mfma_f32_16x16x32_bf16(pf0, vf, o_acc[0][dt], 0, 0, 0);
        o_acc[1][dt] = __builtin_amdgcn_mfma_f32_16x16x32_bf16(pf1, vf, o_acc[1][dt], 0, 0, 0);
      }
    }
    __builtin_amdgcn_s_setprio(0);

    // K_{j+1} landed; all waves' Vts reads done -> safe to restage next iter
    asm volatile("s_waitcnt vmcnt(0)" ::: "memory");
    __builtin_amdgcn_s_barrier();
    curoff ^= 8192;
  }

  // reduce l across the 4 lanes sharing each query (fr), once
  float l_red[2];
#pragma unroll
  for (int mt = 0; mt < 2; ++mt) {
    float lv = l2[mt][0] + l2[mt][1];
    lv += __shfl_xor(lv, 16);
    lv += __shfl_xor(lv, 32);
    l_red[mt] = lv;
  }

  // epilogue: normalize, write context [b][s][h*64+d] bf16
  const int b = bh >> 4;
  const int h = bh & 15;
#pragma unroll
  for (int mt = 0; mt < 2; ++mt) {
#pragma unroll
    for (int r = 0; r < 4; ++r) {
      float lv = __shfl(l_red[mt], qd * 4 + r);
      float rl = 1.0f / lv;
      int s = q0 + wq * 32 + mt * 16 + qd * 4 + r;
      size_t base = (((size_t)b * 2048 + s) << 10) + (h << 6);
#pragma unroll
      for (int dt = 0; dt < 4; ++dt) Ctx[base + dt * 16 + fr] = f2bf(o_acc[mt][dt][r] * rl);
    }
  }
}

// ---------------- output projection GEMM (f32 out) ----------------
// r13: same dbuf pipeline + paired-row XOR swizzle as k_gemm_qkv.
__global__ __launch_bounds__(256, 3) void k_gemm_out(
    const unsigned short* __restrict__ Ctx, const unsigned short* __restrict__ Wo,
    const float* __restrict__ bo, float* __restrict__ out) {
  __shared__ unsigned short As[2 * 4096];
  __shared__ unsigned short Bs[2 * 4096];
  const int tid = threadIdx.x;
  const int lane = tid & 63;
  const int w = tid >> 6;
  const int wm = w & 1;
  const int wn = w >> 1;
  const int lin = blockIdx.x + (blockIdx.y << 3);
  const int swz = ((lin & 7) << 6) + (lin >> 3);
  const int m0 = (swz >> 3) << 7;
  const int n0 = (swz & 7) << 7;

  const int sR = tid >> 3;
  const int sc_ = (tid & 7) ^ (sR & 7);
  const int mrow0 = 2 * sR + (sc_ >> 2);
  const int kc0 = (sc_ & 3) << 3;
  const unsigned short* srcA = Ctx + (size_t)(m0 + mrow0) * 1024 + kc0;
  const unsigned short* srcB = Wo + (size_t)(n0 + mrow0) * 1024 + kc0;
  unsigned short* dstA = As + tid * 8;
  unsigned short* dstB = Bs + tid * 8;

  const int fr = lane & 15;
  const int kq = lane >> 4;
  int aoff[4], boff[4];
#pragma unroll
  for (int t = 0; t < 4; ++t) {
    int ra = wm * 64 + t * 16 + fr;
    aoff[t] = ((ra >> 1) << 6) + (((((ra & 1) << 2) + kq) ^ ((ra >> 1) & 7)) << 3);
    int rb = wn * 64 + t * 16 + fr;
    boff[t] = ((rb >> 1) << 6) + (((((rb & 1) << 2) + kq) ^ ((rb >> 1) & 7)) << 3);
  }

  f32x4 zero4 = {0.f, 0.f, 0.f, 0.f};
  f32x4 acc[4][4];
#pragma unroll
  for (int i = 0; i < 4; ++i)
#pragma unroll
    for (int jj = 0; jj < 4; ++jj) acc[i][jj] = zero4;

  gload16(srcA, dstA);
  gload16(srcA + 65536, dstA + 2048);
  gload16(srcB, dstB);
  gload16(srcB + 65536, dstB + 2048);

  int cur = 0;
  for (int kt = 0; kt < 32; ++kt) {
    const int kon = ((kt + 1) & 31) << 5;
    const int soff = (cur ^ 1) << 12;
    gload16(srcA + kon, dstA + soff);
    gload16(srcA + 65536 + kon, dstA + soff + 2048);
    gload16(srcB + kon, dstB + soff);
    gload16(srcB + 65536 + kon, dstB + soff + 2048);

    asm volatile("s_waitcnt vmcnt(4)" ::: "memory");
    __builtin_amdgcn_s_barrier();

    const unsigned short* Ac = As + (cur << 12);
    const unsigned short* Bc = Bs + (cur << 12);
    bf16x8 af[4], bfr[4];
#pragma unroll
    for (int mt = 0; mt < 4; ++mt) af[mt] = *(const bf16x8*)&Ac[aoff[mt]];
#pragma unroll
    for (int nt = 0; nt < 4; ++nt) bfr[nt] = *(const bf16x8*)&Bc[boff[nt]];

    asm volatile("s_waitcnt lgkmcnt(0)" ::: "memory");
    __builtin_amdgcn_s_barrier();

    __builtin_amdgcn_s_setprio(1);
#pragma unroll
    for (int mt = 0; mt < 4; ++mt)
#pragma unroll
      for (int nt = 0; nt < 4; ++nt)
        acc[mt][nt] = __builtin_amdgcn_mfma_f32_16x16x32_bf16(af[mt], bfr[nt], acc[mt][nt], 0, 0, 0);
    __builtin_amdgcn_s_setprio(0);
    cur ^= 1;
  }

  const int rg = kq << 2;
#pragma unroll
  for (int mt = 0; mt < 4; ++mt) {
    const int mb = m0 + wm * 64 + mt * 16 + rg;
#pragma unroll
    for (int nt = 0; nt < 4; ++nt) {
      const int n = n0 + wn * 64 + nt * 16 + fr;
      const float bvv = bo[n];
#pragma unroll
      for (int r = 0; r < 4; ++r)
        out[(size_t)(mb + r) * 1024 + n] = acc[mt][nt][r] + bvv;
    }
  }
}

// ---------------- host ----------------
extern "C" void kernel_launch(void* const* d_in, const int* in_sizes, int n_in,
                              void* d_out, int out_size, void* d_ws, size_t ws_size,
                              hipStream_t stream) {
  (void)in_sizes; (void)n_in; (void)out_size; (void)ws_size;
  const float* x = (const float*)d_in[0];
  const float* Wq = (const float*)d_in[1];
  const float* bq = (const float*)d_in[2];
  const float* Wk = (const float*)d_in[3];
  const float* bk = (const float*)d_in[4];
  const float* Wv = (const float*)d_in[5];
  const float* bv = (const float*)d_in[6];
  const float* Wo = (const float*)d_in[7];
  const float* bo = (const float*)d_in[8];
  float* out = (float*)d_out;

  unsigned short* xb = (unsigned short*)d_ws;  // 8388608 el
  unsigned short* Wb = xb + 8388608;           // 4194304 el (q,k,v,o)
  unsigned short* Qb = Wb + 4194304;           // [b,h,s,d]
  unsigned short* Kb = Qb + 8388608;           // [b,h,s,d]
  unsigned short* Vtb = Kb + 8388608;          // [b,h,d,s_perm]
  unsigned short* Ctx = xb;                    // reuse xb (dead after k_gemm_qkv)

  k_cvt<<<12288, 256, 0, stream>>>(x, Wq, Wk, Wv, Wo, xb, Wb);
  k_gemm_qkv<<<dim3(8, 64, 3), 256, 0, stream>>>(xb, Wb, bq, bk, bv, Qb, Kb, Vtb);
  k_flash<<<dim3(8, 64), 512, 0, stream>>>(Qb, Kb, Vtb, Ctx);
  k_gemm_out<<<dim3(8, 64), 256, 0, stream>>>(Ctx, Wb + 3 * 1048576, bo, out);
}